// Round 1
// baseline (918.036 us; speedup 1.0000x reference)
//
#include <hip/hip_runtime.h>

#define CAP 48
#define BM 64

// ---- build bucketed CSR (by dst) -------------------------------------------
__global__ __launch_bounds__(256) void k_bucket(const int* __restrict__ src, const int* __restrict__ dst,
                                                int E, int* __restrict__ cnt, int* __restrict__ bucket) {
    int e = blockIdx.x * 256 + threadIdx.x;
    if (e < E) {
        int d = dst[e];
        int slot = atomicAdd(&cnt[d], 1);
        if (slot < CAP) bucket[(size_t)d * CAP + slot] = src[e];
    }
}

__global__ __launch_bounds__(256) void k_invdeg(const int* __restrict__ cnt, float* __restrict__ invdeg, int n) {
    int i = blockIdx.x * 256 + threadIdx.x;
    if (i < n) invdeg[i] = 1.0f / fmaxf((float)cnt[i], 1.0f);
}

// ---- fold BN(eval) + bias into per-column scale/shift ----------------------
__global__ void k_prep(const float* g1, const float* be1, const float* rm1, const float* rv1, const float* bl1,
                       const float* g2, const float* be2, const float* rm2, const float* rv2, const float* bl2,
                       float* P) {
    int j = threadIdx.x;  // 128 threads
    float s1 = g1[j] * rsqrtf(rv1[j] + 1e-5f);
    P[j]       = s1;
    P[128 + j] = (bl1[j] - rm1[j]) * s1 + be1[j];
    float s2 = g2[j] * rsqrtf(rv2[j] + 1e-5f);
    P[256 + j] = s2;
    P[384 + j] = (bl2[j] - rm2[j]) * s2 + be2[j];
}

// ---- pull-style mean aggregation: one wave per node ------------------------
template<int D>
__global__ __launch_bounds__(256) void k_agg(const float* __restrict__ in, const int* __restrict__ cnt,
                                             const int* __restrict__ bucket, const float* __restrict__ invdeg,
                                             float* __restrict__ out, int n) {
    int wid = (blockIdx.x * 256 + threadIdx.x) >> 6;
    int lane = threadIdx.x & 63;
    if (wid >= n) return;
    int c = cnt[wid]; if (c > CAP) c = CAP;
    const int* bk = bucket + (size_t)wid * CAP;
    float iv = invdeg[wid];
    if (D == 128) {
        float ax = 0.f, ay = 0.f;
        for (int s = 0; s < c; s++) {
            int sr = bk[s];
            float2 v = *((const float2*)(in + (size_t)sr * 128) + lane);
            ax += v.x; ay += v.y;
        }
        float2 o; o.x = ax * iv; o.y = ay * iv;
        *((float2*)(out + (size_t)wid * 128) + lane) = o;
    } else {
        float a = 0.f;
        for (int s = 0; s < c; s++) {
            int sr = bk[s];
            a += in[(size_t)sr * 64 + lane];
        }
        out[(size_t)wid * 64 + lane] = a * iv;
    }
}

// ---- fp32 GEMM, K=128 fixed, optional dual A@B + A2@B2, fused epilogue -----
// out[r][j] = (A@B)[r][j] (+ (A2@B2)[r][j]) (+ Dadd[r][j]) (+ shift[j] bias)
//             (RELU: relu(v*scale[j] + shift[j]))
template<int JD, bool DUAL, bool RELU, bool ADDD, bool BIAS>
__global__ __launch_bounds__(256) void k_gemm(const float* __restrict__ A, const float* __restrict__ B,
                                              const float* __restrict__ A2, const float* __restrict__ B2,
                                              const float* __restrict__ Dadd, const float* __restrict__ scale,
                                              const float* __restrict__ shift, float* __restrict__ out, int nrows) {
    __shared__ float ldsA[BM * 128];
    __shared__ float ldsA2[DUAL ? BM * 128 : 4];
    const int tid = threadIdx.x;
    const int row0 = blockIdx.x * BM;

    // stage A (and A2) tile: BM x 128, row-major, float4 coalesced
    #pragma unroll
    for (int i = 0; i < BM * 32; i += 256) {
        int f = i + tid;           // float4 index in tile
        int r = f >> 5, c4 = (f & 31) << 2;
        bool ok = (row0 + r) < nrows;
        float4 v = ok ? *(const float4*)(A + (size_t)(row0 + r) * 128 + c4) : make_float4(0.f, 0.f, 0.f, 0.f);
        *(float4*)(&ldsA[f << 2]) = v;
        if constexpr (DUAL) {
            float4 v2 = ok ? *(const float4*)(A2 + (size_t)(row0 + r) * 128 + c4) : make_float4(0.f, 0.f, 0.f, 0.f);
            *(float4*)(&ldsA2[f << 2]) = v2;
        }
    }
    __syncthreads();

    constexpr int NC = JD / 64;    // columns per thread (2 for JD=128, 1 for JD=64)
    const int j0 = tid & 63;
    const int rg = tid >> 6;       // row group 0..3
    float acc[NC][16];
    #pragma unroll
    for (int c = 0; c < NC; c++)
        #pragma unroll
        for (int m = 0; m < 16; m++) acc[c][m] = 0.f;

    for (int k0 = 0; k0 < 128; k0 += 4) {
        float b[NC][4], b2[NC][4];
        #pragma unroll
        for (int c = 0; c < NC; c++) {
            int j = j0 + c * 64;
            #pragma unroll
            for (int kk = 0; kk < 4; kk++) {
                b[c][kk] = B[(size_t)(k0 + kk) * JD + j];
                if constexpr (DUAL) b2[c][kk] = B2[(size_t)(k0 + kk) * JD + j];
            }
        }
        #pragma unroll
        for (int m = 0; m < 16; m++) {
            int r = rg + (m << 2);
            float4 av = *(const float4*)(&ldsA[r * 128 + k0]);
            #pragma unroll
            for (int c = 0; c < NC; c++)
                acc[c][m] += av.x * b[c][0] + av.y * b[c][1] + av.z * b[c][2] + av.w * b[c][3];
            if constexpr (DUAL) {
                float4 av2 = *(const float4*)(&ldsA2[r * 128 + k0]);
                #pragma unroll
                for (int c = 0; c < NC; c++)
                    acc[c][m] += av2.x * b2[c][0] + av2.y * b2[c][1] + av2.z * b2[c][2] + av2.w * b2[c][3];
            }
        }
    }

    #pragma unroll
    for (int m = 0; m < 16; m++) {
        int r = row0 + rg + (m << 2);
        if (r < nrows) {
            #pragma unroll
            for (int c = 0; c < NC; c++) {
                int j = j0 + c * 64;
                float v = acc[c][m];
                if constexpr (ADDD) v += Dadd[(size_t)r * JD + j];
                if constexpr (BIAS) v += shift[j];
                if constexpr (RELU) v = fmaxf(v * scale[j] + shift[j], 0.f);
                out[(size_t)r * JD + j] = v;
            }
        }
    }
}

extern "C" void kernel_launch(void* const* d_in, const int* in_sizes, int n_in,
                              void* d_out, int out_size, void* d_ws, size_t ws_size,
                              hipStream_t stream) {
    const float* x   = (const float*)d_in[0];
    const int*   ei  = (const int*)d_in[1];
    const float* Wl1 = (const float*)d_in[2];
    const float* bl1 = (const float*)d_in[3];
    const float* Wr1 = (const float*)d_in[4];
    const float* g1  = (const float*)d_in[5];
    const float* be1 = (const float*)d_in[6];
    const float* rm1 = (const float*)d_in[7];
    const float* rv1 = (const float*)d_in[8];
    const float* Wl2 = (const float*)d_in[9];
    const float* bl2 = (const float*)d_in[10];
    const float* Wr2 = (const float*)d_in[11];
    const float* g2  = (const float*)d_in[12];
    const float* be2 = (const float*)d_in[13];
    const float* rm2 = (const float*)d_in[14];
    const float* rv2 = (const float*)d_in[15];
    const float* Wl3 = (const float*)d_in[16];
    const float* bl3 = (const float*)d_in[17];
    const float* Wr3 = (const float*)d_in[18];

    const int N = in_sizes[0] / 128;
    const int E = in_sizes[1] / 2;
    const int* src = ei;
    const int* dst = ei + E;

    // workspace layout
    char* w = (char*)d_ws;
    auto au = [](size_t v) { return (v + 1023) & ~(size_t)1023; };
    size_t off = 0;
    int*   cnt    = (int*)(w + off);  off += au((size_t)N * 4);
    float* invdeg = (float*)(w + off); off += au((size_t)N * 4);
    int*   bucket = (int*)(w + off);  off += au((size_t)N * CAP * 4);
    float* agg    = (float*)(w + off); off += au((size_t)N * 128 * 4);
    float* h      = (float*)(w + off); off += au((size_t)N * 128 * 4);
    float* t3     = (float*)(w + off); off += au((size_t)N * 64 * 4);
    float* P      = (float*)(w + off); off += 2048;
    (void)ws_size; (void)n_in;

    hipMemsetAsync(cnt, 0, (size_t)N * 4, stream);
    k_bucket<<<(E + 255) / 256, 256, 0, stream>>>(src, dst, E, cnt, bucket);
    k_invdeg<<<(N + 255) / 256, 256, 0, stream>>>(cnt, invdeg, N);
    k_prep<<<1, 128, 0, stream>>>(g1, be1, rm1, rv1, bl1, g2, be2, rm2, rv2, bl2, P);

    const int aggGrid  = ((size_t)N * 64 + 255) / 256;  // one wave per node
    const int gemmGrid = (N + BM - 1) / BM;

    // layer 1: h = relu(bn(agg(x)@Wl1 + bl1 + x@Wr1))
    k_agg<128><<<aggGrid, 256, 0, stream>>>(x, cnt, bucket, invdeg, agg, N);
    k_gemm<128, true, true, false, false><<<gemmGrid, 256, 0, stream>>>(
        agg, Wl1, x, Wr1, nullptr, P, P + 128, h, N);

    // layer 2: h = relu(bn(agg(h)@Wl2 + bl2 + h@Wr2))   (in-place on h: block reads own rows to LDS first)
    k_agg<128><<<aggGrid, 256, 0, stream>>>(h, cnt, bucket, invdeg, agg, N);
    k_gemm<128, true, true, false, false><<<gemmGrid, 256, 0, stream>>>(
        agg, Wl2, h, Wr2, nullptr, P + 256, P + 384, h, N);

    // layer 3: out = agg(h@Wl3) + bl3 + h@Wr3   (transform-then-aggregate, 64-dim edges)
    k_gemm<64, false, false, false, false><<<gemmGrid, 256, 0, stream>>>(
        h, Wl3, nullptr, nullptr, nullptr, nullptr, nullptr, t3, N);
    k_agg<64><<<aggGrid, 256, 0, stream>>>(t3, cnt, bucket, invdeg, agg, N);
    k_gemm<64, false, false, true, true><<<gemmGrid, 256, 0, stream>>>(
        h, Wr3, nullptr, nullptr, agg, nullptr, bl3, (float*)d_out, N);
}

// Round 3
// 485.039 us; speedup vs baseline: 1.8927x; 1.8927x over previous
//
#include <hip/hip_runtime.h>

#define CAP 48

typedef short  s8v  __attribute__((ext_vector_type(8)));
typedef float  f4v  __attribute__((ext_vector_type(4)));

__device__ __forceinline__ unsigned short f2bf(float f) {
    unsigned u = __float_as_uint(f);
    u += 0x7FFFu + ((u >> 16) & 1u);      // RNE
    return (unsigned short)(u >> 16);
}
__device__ __forceinline__ float bf2f(unsigned short b) {
    return __uint_as_float(((unsigned)b) << 16);
}

// ---- build bucketed CSR (by dst) -------------------------------------------
__global__ __launch_bounds__(256) void k_bucket(const int* __restrict__ src, const int* __restrict__ dst,
                                                int E, int* __restrict__ cnt, int* __restrict__ bucket) {
    int e = blockIdx.x * 256 + threadIdx.x;
    if (e < E) {
        int d = dst[e];
        int slot = atomicAdd(&cnt[d], 1);
        if (slot < CAP) bucket[(size_t)d * CAP + slot] = src[e];
    }
}

__global__ __launch_bounds__(256) void k_invdeg(const int* __restrict__ cnt, float* __restrict__ invdeg, int n) {
    int i = blockIdx.x * 256 + threadIdx.x;
    if (i < n) invdeg[i] = 1.0f / fmaxf((float)cnt[i], 1.0f);
}

// ---- fold BN(eval) + bias into per-column scale/shift ----------------------
__global__ void k_prep(const float* g1, const float* be1, const float* rm1, const float* rv1, const float* bl1,
                       const float* g2, const float* be2, const float* rm2, const float* rv2, const float* bl2,
                       float* P) {
    int j = threadIdx.x;  // 128 threads
    float s1 = g1[j] * rsqrtf(rv1[j] + 1e-5f);
    P[j]       = s1;
    P[128 + j] = (bl1[j] - rm1[j]) * s1 + be1[j];
    float s2 = g2[j] * rsqrtf(rv2[j] + 1e-5f);
    P[256 + j] = s2;
    P[384 + j] = (bl2[j] - rm2[j]) * s2 + be2[j];
}

// ---- fp32 -> bf16 row-major convert ----------------------------------------
__global__ __launch_bounds__(256) void k_cvt(const float* __restrict__ in, unsigned short* __restrict__ out, int n4) {
    int i = blockIdx.x * 256 + threadIdx.x;
    if (i < n4) {
        float4 v = ((const float4*)in)[i];
        ushort4 o;
        o.x = f2bf(v.x); o.y = f2bf(v.y); o.z = f2bf(v.z); o.w = f2bf(v.w);
        ((ushort4*)out)[i] = o;
    }
}

// ---- pack weight W[K=128][JD] fp32 -> MFMA B-fragment order bf16 -----------
// pack[((kt*(JD/16)+nt)*64 + lane)*8 + j] = W[kt*32 + (lane>>4)*8 + j][nt*16 + (lane&15)]
__global__ __launch_bounds__(256) void k_packW(const float* W0, const float* W1, const float* W2,
                                               const float* W3, const float* W4, const float* W5,
                                               unsigned short* P0, unsigned short* P1, unsigned short* P2,
                                               unsigned short* P3, unsigned short* P4, unsigned short* P5) {
    const float* W; unsigned short* P; int JD;
    switch (blockIdx.y) {
        case 0: W = W0; P = P0; JD = 128; break;
        case 1: W = W1; P = P1; JD = 128; break;
        case 2: W = W2; P = P2; JD = 128; break;
        case 3: W = W3; P = P3; JD = 128; break;
        case 4: W = W4; P = P4; JD = 64;  break;
        default:W = W5; P = P5; JD = 64;  break;
    }
    int o = blockIdx.x * 256 + threadIdx.x;
    if (o >= 128 * JD) return;
    int j    = o & 7;
    int lane = (o >> 3) & 63;
    int t    = o >> 9;
    int nt   = t % (JD / 16);
    int kt   = t / (JD / 16);
    int k = kt * 32 + (lane >> 4) * 8 + j;
    int n = nt * 16 + (lane & 15);
    P[o] = f2bf(W[(size_t)k * JD + n]);
}

// ---- pull-style mean aggregation, bf16 in ----------------------------------
// one wave per node; D=128: bf16 in -> bf16 out; D=64: bf16 in -> fp32 out
__global__ __launch_bounds__(256) void k_agg128b(const unsigned short* __restrict__ in, const int* __restrict__ cnt,
                                                 const int* __restrict__ bucket, const float* __restrict__ invdeg,
                                                 unsigned int* __restrict__ out, int n) {
    int wid = (blockIdx.x * 256 + threadIdx.x) >> 6;
    int lane = threadIdx.x & 63;
    if (wid >= n) return;
    int c = cnt[wid]; if (c > CAP) c = CAP;
    const int* bk = bucket + (size_t)wid * CAP;
    float iv = invdeg[wid];
    float a0 = 0.f, a1 = 0.f;
    for (int s = 0; s < c; s++) {
        int sr = bk[s];
        unsigned v = ((const unsigned*)(in + (size_t)sr * 128))[lane];
        a0 += __uint_as_float(v << 16);          // even element
        a1 += __uint_as_float(v & 0xffff0000u);  // odd element
    }
    a0 *= iv; a1 *= iv;
    out[(size_t)wid * 64 + lane] = (unsigned)f2bf(a0) | ((unsigned)f2bf(a1) << 16);
}

__global__ __launch_bounds__(256) void k_agg64b(const unsigned short* __restrict__ in, const int* __restrict__ cnt,
                                                const int* __restrict__ bucket, const float* __restrict__ invdeg,
                                                float* __restrict__ out, int n) {
    int wid = (blockIdx.x * 256 + threadIdx.x) >> 6;
    int lane = threadIdx.x & 63;
    if (wid >= n) return;
    int c = cnt[wid]; if (c > CAP) c = CAP;
    const int* bk = bucket + (size_t)wid * CAP;
    float iv = invdeg[wid];
    float a = 0.f;
    for (int s = 0; s < c; s++) {
        int sr = bk[s];
        a += bf2f(in[(size_t)sr * 64 + lane]);
    }
    out[(size_t)wid * 64 + lane] = a * iv;
}

// ---- MFMA GEMM: [nrows x 128] bf16 @ packed B -> [nrows x JD] --------------
// optional dual (A@B + A2@B2 into same acc), fused epilogue.
// per block: 256 threads = 4 waves, each wave 32 rows (2 m-tiles), block 128 rows.
template<int JD, bool DUAL, bool RELU, bool ADDD, bool BIAS, bool OUTF, bool OUTB>
__global__ __launch_bounds__(256) void k_mfma(const unsigned short* __restrict__ A, const unsigned short* __restrict__ Bp,
                                              const unsigned short* __restrict__ A2, const unsigned short* __restrict__ B2p,
                                              const float* __restrict__ Dadd, const float* __restrict__ scale,
                                              const float* __restrict__ shift, float* __restrict__ outf,
                                              unsigned short* __restrict__ outb, int nrows) {
    constexpr int NT = JD / 16;
    const int tid  = threadIdx.x;
    const int wave = tid >> 6;
    const int lane = tid & 63;
    const int rw0  = blockIdx.x * 128 + wave * 32;
    if (rw0 >= nrows) return;

    const int m = lane & 15;
    const int q = lane >> 4;
    const int rA0 = min(rw0 + m,      nrows - 1);
    const int rA1 = min(rw0 + 16 + m, nrows - 1);

    f4v acc[2][NT];
    #pragma unroll
    for (int mt = 0; mt < 2; mt++)
        #pragma unroll
        for (int nt = 0; nt < NT; nt++) {
            acc[mt][nt][0] = 0.f; acc[mt][nt][1] = 0.f; acc[mt][nt][2] = 0.f; acc[mt][nt][3] = 0.f;
        }

    #pragma unroll
    for (int kt = 0; kt < 4; kt++) {
        const int ko = kt * 32 + q * 8;
        s8v a0 = *(const s8v*)(A + (size_t)rA0 * 128 + ko);
        s8v a1 = *(const s8v*)(A + (size_t)rA1 * 128 + ko);
        s8v a0d, a1d;
        if constexpr (DUAL) {
            a0d = *(const s8v*)(A2 + (size_t)rA0 * 128 + ko);
            a1d = *(const s8v*)(A2 + (size_t)rA1 * 128 + ko);
        }
        #pragma unroll
        for (int nt = 0; nt < NT; nt++) {
            s8v b = *(const s8v*)(Bp + ((size_t)(kt * NT + nt) * 64 + lane) * 8);
            acc[0][nt] = __builtin_amdgcn_mfma_f32_16x16x32_bf16(a0, b, acc[0][nt], 0, 0, 0);
            acc[1][nt] = __builtin_amdgcn_mfma_f32_16x16x32_bf16(a1, b, acc[1][nt], 0, 0, 0);
            if constexpr (DUAL) {
                s8v b2 = *(const s8v*)(B2p + ((size_t)(kt * NT + nt) * 64 + lane) * 8);
                acc[0][nt] = __builtin_amdgcn_mfma_f32_16x16x32_bf16(a0d, b2, acc[0][nt], 0, 0, 0);
                acc[1][nt] = __builtin_amdgcn_mfma_f32_16x16x32_bf16(a1d, b2, acc[1][nt], 0, 0, 0);
            }
        }
    }

    // epilogue: D element [row = rw0 + mt*16 + q*4 + reg][col = nt*16 + m]
    float scv[NT], shv[NT];
    #pragma unroll
    for (int nt = 0; nt < NT; nt++) {
        int col = nt * 16 + m;
        if constexpr (RELU) scv[nt] = scale[col];
        if constexpr (RELU || BIAS) shv[nt] = shift[col];
    }
    #pragma unroll
    for (int mt = 0; mt < 2; mt++) {
        #pragma unroll
        for (int reg = 0; reg < 4; reg++) {
            int row = rw0 + mt * 16 + q * 4 + reg;
            if (row < nrows) {
                #pragma unroll
                for (int nt = 0; nt < NT; nt++) {
                    int col = nt * 16 + m;
                    float v = acc[mt][nt][reg];
                    if constexpr (ADDD) v += Dadd[(size_t)row * JD + col];
                    if constexpr (BIAS) v += shv[nt];
                    if constexpr (RELU) v = fmaxf(v * scv[nt] + shv[nt], 0.f);
                    if constexpr (OUTF) outf[(size_t)row * JD + col] = v;
                    if constexpr (OUTB) outb[(size_t)row * JD + col] = f2bf(v);
                }
            }
        }
    }
}

extern "C" void kernel_launch(void* const* d_in, const int* in_sizes, int n_in,
                              void* d_out, int out_size, void* d_ws, size_t ws_size,
                              hipStream_t stream) {
    const float* x   = (const float*)d_in[0];
    const int*   ei  = (const int*)d_in[1];
    const float* Wl1 = (const float*)d_in[2];
    const float* bl1 = (const float*)d_in[3];
    const float* Wr1 = (const float*)d_in[4];
    const float* g1  = (const float*)d_in[5];
    const float* be1 = (const float*)d_in[6];
    const float* rm1 = (const float*)d_in[7];
    const float* rv1 = (const float*)d_in[8];
    const float* Wl2 = (const float*)d_in[9];
    const float* bl2 = (const float*)d_in[10];
    const float* Wr2 = (const float*)d_in[11];
    const float* g2  = (const float*)d_in[12];
    const float* be2 = (const float*)d_in[13];
    const float* rm2 = (const float*)d_in[14];
    const float* rv2 = (const float*)d_in[15];
    const float* Wl3 = (const float*)d_in[16];
    const float* bl3 = (const float*)d_in[17];
    const float* Wr3 = (const float*)d_in[18];

    const int N = in_sizes[0] / 128;
    const int E = in_sizes[1] / 2;
    const int* src = ei;
    const int* dst = ei + E;

    // workspace layout
    char* w = (char*)d_ws;
    auto au = [](size_t v) { return (v + 1023) & ~(size_t)1023; };
    size_t off = 0;
    int*            cnt    = (int*)(w + off);            off += au((size_t)N * 4);
    float*          invdeg = (float*)(w + off);          off += au((size_t)N * 4);
    int*            bucket = (int*)(w + off);            off += au((size_t)N * CAP * 4);
    unsigned short* xb     = (unsigned short*)(w + off); off += au((size_t)N * 128 * 2);
    unsigned short* aggb   = (unsigned short*)(w + off); off += au((size_t)N * 128 * 2);
    unsigned short* hb     = (unsigned short*)(w + off); off += au((size_t)N * 128 * 2);
    unsigned short* hb2    = (unsigned short*)(w + off); off += au((size_t)N * 128 * 2);
    unsigned short* t3b    = (unsigned short*)(w + off); off += au((size_t)N * 64 * 2);
    float*          agg3   = (float*)(w + off);          off += au((size_t)N * 64 * 4);
    unsigned short* Wp[6];
    Wp[0] = (unsigned short*)(w + off); off += au(128 * 128 * 2);  // Wl1
    Wp[1] = (unsigned short*)(w + off); off += au(128 * 128 * 2);  // Wr1
    Wp[2] = (unsigned short*)(w + off); off += au(128 * 128 * 2);  // Wl2
    Wp[3] = (unsigned short*)(w + off); off += au(128 * 128 * 2);  // Wr2
    Wp[4] = (unsigned short*)(w + off); off += au(128 * 64 * 2);   // Wl3
    Wp[5] = (unsigned short*)(w + off); off += au(128 * 64 * 2);   // Wr3
    float* P = (float*)(w + off); off += 2048;
    (void)ws_size; (void)n_in;

    hipMemsetAsync(cnt, 0, (size_t)N * 4, stream);
    k_bucket<<<(E + 255) / 256, 256, 0, stream>>>(src, dst, E, cnt, bucket);
    k_invdeg<<<(N + 255) / 256, 256, 0, stream>>>(cnt, invdeg, N);
    k_prep<<<1, 128, 0, stream>>>(g1, be1, rm1, rv1, bl1, g2, be2, rm2, rv2, bl2, P);
    dim3 pg(64, 6);
    k_packW<<<pg, 256, 0, stream>>>(Wl1, Wr1, Wl2, Wr2, Wl3, Wr3,
                                    Wp[0], Wp[1], Wp[2], Wp[3], Wp[4], Wp[5]);
    k_cvt<<<((N * 128 / 4) + 255) / 256, 256, 0, stream>>>(x, xb, N * 128 / 4);

    const int aggGrid  = ((size_t)N * 64 + 255) / 256;  // one wave per node
    const int gemmGrid = (N + 127) / 128;

    // layer 1: hb = relu(bn(agg(x)@Wl1 + bl1 + x@Wr1))        [bf16 out]
    k_agg128b<<<aggGrid, 256, 0, stream>>>(xb, cnt, bucket, invdeg, (unsigned int*)aggb, N);
    k_mfma<128, true, true, false, false, false, true><<<gemmGrid, 256, 0, stream>>>(
        aggb, Wp[0], xb, Wp[1], nullptr, P, P + 128, nullptr, hb, N);

    // layer 2: hb2 = relu(bn(agg(hb)@Wl2 + bl2 + hb@Wr2))     [bf16 out]
    k_agg128b<<<aggGrid, 256, 0, stream>>>(hb, cnt, bucket, invdeg, (unsigned int*)aggb, N);
    k_mfma<128, true, true, false, false, false, true><<<gemmGrid, 256, 0, stream>>>(
        aggb, Wp[2], hb, Wp[3], nullptr, P + 256, P + 384, nullptr, hb2, N);

    // layer 3: out = agg(hb2@Wl3) + bl3 + hb2@Wr3   (transform-then-aggregate)
    k_mfma<64, false, false, false, false, false, true><<<gemmGrid, 256, 0, stream>>>(
        hb2, Wp[4], nullptr, nullptr, nullptr, nullptr, nullptr, nullptr, t3b, N);
    k_agg64b<<<aggGrid, 256, 0, stream>>>(t3b, cnt, bucket, invdeg, agg3, N);
    k_mfma<64, false, false, true, true, true, false><<<gemmGrid, 256, 0, stream>>>(
        hb2, Wp[5], nullptr, nullptr, agg3, nullptr, bl3, (float*)d_out, nullptr, N);
}

// Round 4
// 358.320 us; speedup vs baseline: 2.5621x; 1.3536x over previous
//
#include <hip/hip_runtime.h>

#define CAP 48

typedef short  s8v  __attribute__((ext_vector_type(8)));
typedef float  f4v  __attribute__((ext_vector_type(4)));

__device__ __forceinline__ unsigned short f2bf(float f) {
    unsigned u = __float_as_uint(f);
    u += 0x7FFFu + ((u >> 16) & 1u);      // RNE
    return (unsigned short)(u >> 16);
}
__device__ __forceinline__ float bflo(unsigned v) { return __uint_as_float(v << 16); }
__device__ __forceinline__ float bfhi(unsigned v) { return __uint_as_float(v & 0xffff0000u); }

// ---- build bucketed CSR (by dst) -------------------------------------------
__global__ __launch_bounds__(256) void k_bucket(const int* __restrict__ src, const int* __restrict__ dst,
                                                int E, int* __restrict__ cnt, int* __restrict__ bucket) {
    int e = blockIdx.x * 256 + threadIdx.x;
    if (e < E) {
        int d = dst[e];
        int slot = atomicAdd(&cnt[d], 1);
        if (slot < CAP) bucket[(size_t)d * CAP + slot] = src[e];
    }
}

// ---- fold BN(eval) + bias into per-column scale/shift ----------------------
__global__ void k_prep(const float* g1, const float* be1, const float* rm1, const float* rv1, const float* bl1,
                       const float* g2, const float* be2, const float* rm2, const float* rv2, const float* bl2,
                       float* P) {
    int j = threadIdx.x;  // 128 threads
    float s1 = g1[j] * rsqrtf(rv1[j] + 1e-5f);
    P[j]       = s1;
    P[128 + j] = (bl1[j] - rm1[j]) * s1 + be1[j];
    float s2 = g2[j] * rsqrtf(rv2[j] + 1e-5f);
    P[256 + j] = s2;
    P[384 + j] = (bl2[j] - rm2[j]) * s2 + be2[j];
}

// ---- fp32 -> bf16 row-major convert ----------------------------------------
__global__ __launch_bounds__(256) void k_cvt(const float* __restrict__ in, unsigned short* __restrict__ out, int n4) {
    int i = blockIdx.x * 256 + threadIdx.x;
    if (i < n4) {
        float4 v = ((const float4*)in)[i];
        ushort4 o;
        o.x = f2bf(v.x); o.y = f2bf(v.y); o.z = f2bf(v.z); o.w = f2bf(v.w);
        ((ushort4*)out)[i] = o;
    }
}

// ---- pack weight W[K=128][JD] fp32 -> MFMA B-fragment order bf16 -----------
__global__ __launch_bounds__(256) void k_packW(const float* W0, const float* W1, const float* W2,
                                               const float* W3, const float* W4, const float* W5,
                                               unsigned short* P0, unsigned short* P1, unsigned short* P2,
                                               unsigned short* P3, unsigned short* P4, unsigned short* P5) {
    const float* W; unsigned short* P; int JD;
    switch (blockIdx.y) {
        case 0: W = W0; P = P0; JD = 128; break;
        case 1: W = W1; P = P1; JD = 128; break;
        case 2: W = W2; P = P2; JD = 128; break;
        case 3: W = W3; P = P3; JD = 128; break;
        case 4: W = W4; P = P4; JD = 64;  break;
        default:W = W5; P = P5; JD = 64;  break;
    }
    int o = blockIdx.x * 256 + threadIdx.x;
    if (o >= 128 * JD) return;
    int j    = o & 7;
    int lane = (o >> 3) & 63;
    int t    = o >> 9;
    int nt   = t % (JD / 16);
    int kt   = t / (JD / 16);
    int k = kt * 32 + (lane >> 4) * 8 + j;
    int n = nt * 16 + (lane & 15);
    P[o] = f2bf(W[(size_t)k * JD + n]);
}

// ---- pull-style mean aggregation, D=128 bf16 -> bf16 -----------------------
// 2 nodes per wave (32 lanes x uint2 = 256B row); indices preloaded + shfl;
// gather loop unrolled x4 for memory-level parallelism.
__global__ __launch_bounds__(256) void k_agg128b(const unsigned short* __restrict__ in, const int* __restrict__ cnt,
                                                 const int* __restrict__ bucket, uint2* __restrict__ out, int n) {
    int wv   = (blockIdx.x * 256 + threadIdx.x) >> 6;
    int lane = threadIdx.x & 63;
    int g    = lane >> 5;          // node slot in wave
    int li   = lane & 31;
    int node = wv * 2 + g;
    if (node >= n) return;
    int c = cnt[node]; if (c > CAP) c = CAP;
    const uint2* inp = (const uint2*)in;   // row = 32 granules of 8B
    int idxv = 0;
    if (li < c) idxv = bucket[(size_t)node * CAP + li];   // covers s<32
    float a0 = 0.f, a1 = 0.f, a2 = 0.f, a3 = 0.f;
    const int base = g << 5;
    int cc = c < 32 ? c : 32;
    int s = 0;
    for (; s + 4 <= cc; s += 4) {
        int i0 = __shfl(idxv, base + s);
        int i1 = __shfl(idxv, base + s + 1);
        int i2 = __shfl(idxv, base + s + 2);
        int i3 = __shfl(idxv, base + s + 3);
        uint2 v0 = inp[(size_t)i0 * 32 + li];
        uint2 v1 = inp[(size_t)i1 * 32 + li];
        uint2 v2 = inp[(size_t)i2 * 32 + li];
        uint2 v3 = inp[(size_t)i3 * 32 + li];
        a0 += bflo(v0.x) + bflo(v1.x) + bflo(v2.x) + bflo(v3.x);
        a1 += bfhi(v0.x) + bfhi(v1.x) + bfhi(v2.x) + bfhi(v3.x);
        a2 += bflo(v0.y) + bflo(v1.y) + bflo(v2.y) + bflo(v3.y);
        a3 += bfhi(v0.y) + bfhi(v1.y) + bfhi(v2.y) + bfhi(v3.y);
    }
    for (; s < cc; s++) {
        int i0 = __shfl(idxv, base + s);
        uint2 v0 = inp[(size_t)i0 * 32 + li];
        a0 += bflo(v0.x); a1 += bfhi(v0.x); a2 += bflo(v0.y); a3 += bfhi(v0.y);
    }
    for (; s < c; s++) {   // c>32: statistically near-impossible, but correct
        int i0 = bucket[(size_t)node * CAP + s];
        uint2 v0 = inp[(size_t)i0 * 32 + li];
        a0 += bflo(v0.x); a1 += bfhi(v0.x); a2 += bflo(v0.y); a3 += bfhi(v0.y);
    }
    float iv = 1.0f / fmaxf((float)c, 1.0f);
    a0 *= iv; a1 *= iv; a2 *= iv; a3 *= iv;
    uint2 o;
    o.x = (unsigned)f2bf(a0) | ((unsigned)f2bf(a1) << 16);
    o.y = (unsigned)f2bf(a2) | ((unsigned)f2bf(a3) << 16);
    out[(size_t)node * 32 + li] = o;
}

// ---- pull-style mean aggregation, D=64 bf16 -> fp32 ------------------------
// 4 nodes per wave (16 lanes x uint2 = 128B row)
__global__ __launch_bounds__(256) void k_agg64b(const unsigned short* __restrict__ in, const int* __restrict__ cnt,
                                                const int* __restrict__ bucket, float4* __restrict__ out, int n) {
    int wv   = (blockIdx.x * 256 + threadIdx.x) >> 6;
    int lane = threadIdx.x & 63;
    int g    = lane >> 4;
    int li   = lane & 15;
    int node = wv * 4 + g;
    if (node >= n) return;
    int c = cnt[node]; if (c > CAP) c = CAP;
    const uint2* inp = (const uint2*)in;   // row = 16 granules of 8B
    int idxv = 0;
    if (li < c) idxv = bucket[(size_t)node * CAP + li];   // covers s<16
    float a0 = 0.f, a1 = 0.f, a2 = 0.f, a3 = 0.f;
    const int base = g << 4;
    int cc = c < 16 ? c : 16;
    int s = 0;
    for (; s + 4 <= cc; s += 4) {
        int i0 = __shfl(idxv, base + s);
        int i1 = __shfl(idxv, base + s + 1);
        int i2 = __shfl(idxv, base + s + 2);
        int i3 = __shfl(idxv, base + s + 3);
        uint2 v0 = inp[(size_t)i0 * 16 + li];
        uint2 v1 = inp[(size_t)i1 * 16 + li];
        uint2 v2 = inp[(size_t)i2 * 16 + li];
        uint2 v3 = inp[(size_t)i3 * 16 + li];
        a0 += bflo(v0.x) + bflo(v1.x) + bflo(v2.x) + bflo(v3.x);
        a1 += bfhi(v0.x) + bfhi(v1.x) + bfhi(v2.x) + bfhi(v3.x);
        a2 += bflo(v0.y) + bflo(v1.y) + bflo(v2.y) + bflo(v3.y);
        a3 += bfhi(v0.y) + bfhi(v1.y) + bfhi(v2.y) + bfhi(v3.y);
    }
    for (; s < cc; s++) {
        int i0 = __shfl(idxv, base + s);
        uint2 v0 = inp[(size_t)i0 * 16 + li];
        a0 += bflo(v0.x); a1 += bfhi(v0.x); a2 += bflo(v0.y); a3 += bfhi(v0.y);
    }
    for (; s < c; s++) {   // c>16 tail (rare)
        int i0 = bucket[(size_t)node * CAP + s];
        uint2 v0 = inp[(size_t)i0 * 16 + li];
        a0 += bflo(v0.x); a1 += bfhi(v0.x); a2 += bflo(v0.y); a3 += bfhi(v0.y);
    }
    float iv = 1.0f / fmaxf((float)c, 1.0f);
    float4 o; o.x = a0 * iv; o.y = a1 * iv; o.z = a2 * iv; o.w = a3 * iv;
    out[(size_t)node * 16 + li] = o;
}

// ---- MFMA GEMM: [nrows x 128] bf16 @ packed B -> [nrows x JD] --------------
template<int JD, bool DUAL, bool RELU, bool ADDD, bool BIAS, bool OUTF, bool OUTB>
__global__ __launch_bounds__(256) void k_mfma(const unsigned short* __restrict__ A, const unsigned short* __restrict__ Bp,
                                              const unsigned short* __restrict__ A2, const unsigned short* __restrict__ B2p,
                                              const float* __restrict__ Dadd, const float* __restrict__ scale,
                                              const float* __restrict__ shift, float* __restrict__ outf,
                                              unsigned short* __restrict__ outb, int nrows) {
    constexpr int NT = JD / 16;
    const int tid  = threadIdx.x;
    const int wave = tid >> 6;
    const int lane = tid & 63;
    const int rw0  = blockIdx.x * 128 + wave * 32;
    if (rw0 >= nrows) return;

    const int m = lane & 15;
    const int q = lane >> 4;
    const int rA0 = min(rw0 + m,      nrows - 1);
    const int rA1 = min(rw0 + 16 + m, nrows - 1);

    f4v acc[2][NT];
    #pragma unroll
    for (int mt = 0; mt < 2; mt++)
        #pragma unroll
        for (int nt = 0; nt < NT; nt++) {
            acc[mt][nt][0] = 0.f; acc[mt][nt][1] = 0.f; acc[mt][nt][2] = 0.f; acc[mt][nt][3] = 0.f;
        }

    #pragma unroll
    for (int kt = 0; kt < 4; kt++) {
        const int ko = kt * 32 + q * 8;
        s8v a0 = *(const s8v*)(A + (size_t)rA0 * 128 + ko);
        s8v a1 = *(const s8v*)(A + (size_t)rA1 * 128 + ko);
        s8v a0d, a1d;
        if constexpr (DUAL) {
            a0d = *(const s8v*)(A2 + (size_t)rA0 * 128 + ko);
            a1d = *(const s8v*)(A2 + (size_t)rA1 * 128 + ko);
        }
        #pragma unroll
        for (int nt = 0; nt < NT; nt++) {
            s8v b = *(const s8v*)(Bp + ((size_t)(kt * NT + nt) * 64 + lane) * 8);
            acc[0][nt] = __builtin_amdgcn_mfma_f32_16x16x32_bf16(a0, b, acc[0][nt], 0, 0, 0);
            acc[1][nt] = __builtin_amdgcn_mfma_f32_16x16x32_bf16(a1, b, acc[1][nt], 0, 0, 0);
            if constexpr (DUAL) {
                s8v b2 = *(const s8v*)(B2p + ((size_t)(kt * NT + nt) * 64 + lane) * 8);
                acc[0][nt] = __builtin_amdgcn_mfma_f32_16x16x32_bf16(a0d, b2, acc[0][nt], 0, 0, 0);
                acc[1][nt] = __builtin_amdgcn_mfma_f32_16x16x32_bf16(a1d, b2, acc[1][nt], 0, 0, 0);
            }
        }
    }

    float scv[NT], shv[NT];
    #pragma unroll
    for (int nt = 0; nt < NT; nt++) {
        int col = nt * 16 + m;
        if constexpr (RELU) scv[nt] = scale[col];
        if constexpr (RELU || BIAS) shv[nt] = shift[col];
    }
    #pragma unroll
    for (int mt = 0; mt < 2; mt++) {
        #pragma unroll
        for (int reg = 0; reg < 4; reg++) {
            int row = rw0 + mt * 16 + q * 4 + reg;
            if (row < nrows) {
                #pragma unroll
                for (int nt = 0; nt < NT; nt++) {
                    int col = nt * 16 + m;
                    float v = acc[mt][nt][reg];
                    if constexpr (ADDD) v += Dadd[(size_t)row * JD + col];
                    if constexpr (BIAS) v += shv[nt];
                    if constexpr (RELU) v = fmaxf(v * scv[nt] + shv[nt], 0.f);
                    if constexpr (OUTF) outf[(size_t)row * JD + col] = v;
                    if constexpr (OUTB) outb[(size_t)row * JD + col] = f2bf(v);
                }
            }
        }
    }
}

extern "C" void kernel_launch(void* const* d_in, const int* in_sizes, int n_in,
                              void* d_out, int out_size, void* d_ws, size_t ws_size,
                              hipStream_t stream) {
    const float* x   = (const float*)d_in[0];
    const int*   ei  = (const int*)d_in[1];
    const float* Wl1 = (const float*)d_in[2];
    const float* bl1 = (const float*)d_in[3];
    const float* Wr1 = (const float*)d_in[4];
    const float* g1  = (const float*)d_in[5];
    const float* be1 = (const float*)d_in[6];
    const float* rm1 = (const float*)d_in[7];
    const float* rv1 = (const float*)d_in[8];
    const float* Wl2 = (const float*)d_in[9];
    const float* bl2 = (const float*)d_in[10];
    const float* Wr2 = (const float*)d_in[11];
    const float* g2  = (const float*)d_in[12];
    const float* be2 = (const float*)d_in[13];
    const float* rm2 = (const float*)d_in[14];
    const float* rv2 = (const float*)d_in[15];
    const float* Wl3 = (const float*)d_in[16];
    const float* bl3 = (const float*)d_in[17];
    const float* Wr3 = (const float*)d_in[18];

    const int N = in_sizes[0] / 128;
    const int E = in_sizes[1] / 2;
    const int* src = ei;
    const int* dst = ei + E;

    // workspace layout
    char* w = (char*)d_ws;
    auto au = [](size_t v) { return (v + 1023) & ~(size_t)1023; };
    size_t off = 0;
    int*            cnt    = (int*)(w + off);            off += au((size_t)N * 4);
    int*            bucket = (int*)(w + off);            off += au((size_t)N * CAP * 4);
    unsigned short* xb     = (unsigned short*)(w + off); off += au((size_t)N * 128 * 2);
    unsigned short* aggb   = (unsigned short*)(w + off); off += au((size_t)N * 128 * 2);
    unsigned short* hb     = (unsigned short*)(w + off); off += au((size_t)N * 128 * 2);
    unsigned short* hb2    = (unsigned short*)(w + off); off += au((size_t)N * 128 * 2);
    unsigned short* t3b    = (unsigned short*)(w + off); off += au((size_t)N * 64 * 2);
    float*          agg3   = (float*)(w + off);          off += au((size_t)N * 64 * 4);
    unsigned short* Wp[6];
    Wp[0] = (unsigned short*)(w + off); off += au(128 * 128 * 2);  // Wl1
    Wp[1] = (unsigned short*)(w + off); off += au(128 * 128 * 2);  // Wr1
    Wp[2] = (unsigned short*)(w + off); off += au(128 * 128 * 2);  // Wl2
    Wp[3] = (unsigned short*)(w + off); off += au(128 * 128 * 2);  // Wr2
    Wp[4] = (unsigned short*)(w + off); off += au(128 * 64 * 2);   // Wl3
    Wp[5] = (unsigned short*)(w + off); off += au(128 * 64 * 2);   // Wr3
    float* P = (float*)(w + off); off += 2048;
    (void)ws_size; (void)n_in;

    hipMemsetAsync(cnt, 0, (size_t)N * 4, stream);
    k_bucket<<<(E + 255) / 256, 256, 0, stream>>>(src, dst, E, cnt, bucket);
    k_prep<<<1, 128, 0, stream>>>(g1, be1, rm1, rv1, bl1, g2, be2, rm2, rv2, bl2, P);
    dim3 pg(64, 6);
    k_packW<<<pg, 256, 0, stream>>>(Wl1, Wr1, Wl2, Wr2, Wl3, Wr3,
                                    Wp[0], Wp[1], Wp[2], Wp[3], Wp[4], Wp[5]);
    k_cvt<<<((N * 128 / 4) + 255) / 256, 256, 0, stream>>>(x, xb, N * 128 / 4);

    const int agg128Grid = ((size_t)N * 32 + 255) / 256;  // 2 nodes/wave
    const int agg64Grid  = ((size_t)N * 16 + 255) / 256;  // 4 nodes/wave
    const int gemmGrid   = (N + 127) / 128;

    // layer 1: hb = relu(bn(agg(x)@Wl1 + bl1 + x@Wr1))        [bf16 out]
    k_agg128b<<<agg128Grid, 256, 0, stream>>>(xb, cnt, bucket, (uint2*)aggb, N);
    k_mfma<128, true, true, false, false, false, true><<<gemmGrid, 256, 0, stream>>>(
        aggb, Wp[0], xb, Wp[1], nullptr, P, P + 128, nullptr, hb, N);

    // layer 2: hb2 = relu(bn(agg(hb)@Wl2 + bl2 + hb@Wr2))     [bf16 out]
    k_agg128b<<<agg128Grid, 256, 0, stream>>>(hb, cnt, bucket, (uint2*)aggb, N);
    k_mfma<128, true, true, false, false, false, true><<<gemmGrid, 256, 0, stream>>>(
        aggb, Wp[2], hb, Wp[3], nullptr, P + 256, P + 384, nullptr, hb2, N);

    // layer 3: out = agg(hb2@Wl3) + bl3 + hb2@Wr3   (transform-then-aggregate)
    k_mfma<64, false, false, false, false, false, true><<<gemmGrid, 256, 0, stream>>>(
        hb2, Wp[4], nullptr, nullptr, nullptr, nullptr, nullptr, nullptr, t3b, N);
    k_agg64b<<<agg64Grid, 256, 0, stream>>>(t3b, cnt, bucket, (float4*)agg3, N);
    k_mfma<64, false, false, true, true, true, false><<<gemmGrid, 256, 0, stream>>>(
        hb2, Wp[5], nullptr, nullptr, agg3, nullptr, bl3, (float*)d_out, nullptr, N);
}

// Round 5
// 346.839 us; speedup vs baseline: 2.6469x; 1.0331x over previous
//
#include <hip/hip_runtime.h>

#define CAP 48

typedef short  s8v  __attribute__((ext_vector_type(8)));
typedef float  f4v  __attribute__((ext_vector_type(4)));

__device__ __forceinline__ unsigned short f2bf(float f) {
    unsigned u = __float_as_uint(f);
    u += 0x7FFFu + ((u >> 16) & 1u);      // RNE
    return (unsigned short)(u >> 16);
}
__device__ __forceinline__ float bflo(unsigned v) { return __uint_as_float(v << 16); }
__device__ __forceinline__ float bfhi(unsigned v) { return __uint_as_float(v & 0xffff0000u); }

// ---- build bucketed CSR (by dst) -------------------------------------------
__global__ __launch_bounds__(256) void k_bucket(const int* __restrict__ src, const int* __restrict__ dst,
                                                int E, int* __restrict__ cnt, int* __restrict__ bucket) {
    int e = blockIdx.x * 256 + threadIdx.x;
    if (e < E) {
        int d = dst[e];
        int slot = atomicAdd(&cnt[d], 1);
        if (slot < CAP) bucket[(size_t)d * CAP + slot] = src[e];
    }
}

// ---- fold BN(eval) + bias into per-column scale/shift ----------------------
__global__ void k_prep(const float* g1, const float* be1, const float* rm1, const float* rv1, const float* bl1,
                       const float* g2, const float* be2, const float* rm2, const float* rv2, const float* bl2,
                       float* P) {
    int j = threadIdx.x;  // 128 threads
    float s1 = g1[j] * rsqrtf(rv1[j] + 1e-5f);
    P[j]       = s1;
    P[128 + j] = (bl1[j] - rm1[j]) * s1 + be1[j];
    float s2 = g2[j] * rsqrtf(rv2[j] + 1e-5f);
    P[256 + j] = s2;
    P[384 + j] = (bl2[j] - rm2[j]) * s2 + be2[j];
}

// ---- fp32 -> bf16 row-major convert ----------------------------------------
__global__ __launch_bounds__(256) void k_cvt(const float* __restrict__ in, unsigned short* __restrict__ out, int n4) {
    int i = blockIdx.x * 256 + threadIdx.x;
    if (i < n4) {
        float4 v = ((const float4*)in)[i];
        ushort4 o;
        o.x = f2bf(v.x); o.y = f2bf(v.y); o.z = f2bf(v.z); o.w = f2bf(v.w);
        ((ushort4*)out)[i] = o;
    }
}

// ---- pack weight W[K=128][JD] fp32 -> MFMA B-fragment order bf16 -----------
__global__ __launch_bounds__(256) void k_packW(const float* W0, const float* W1, const float* W2,
                                               const float* W3, const float* W4, const float* W5,
                                               unsigned short* P0, unsigned short* P1, unsigned short* P2,
                                               unsigned short* P3, unsigned short* P4, unsigned short* P5) {
    const float* W; unsigned short* P; int JD;
    switch (blockIdx.y) {
        case 0: W = W0; P = P0; JD = 128; break;
        case 1: W = W1; P = P1; JD = 128; break;
        case 2: W = W2; P = P2; JD = 128; break;
        case 3: W = W3; P = P3; JD = 128; break;
        case 4: W = W4; P = P4; JD = 64;  break;
        default:W = W5; P = P5; JD = 64;  break;
    }
    int o = blockIdx.x * 256 + threadIdx.x;
    if (o >= 128 * JD) return;
    int j    = o & 7;
    int lane = (o >> 3) & 63;
    int t    = o >> 9;
    int nt   = t % (JD / 16);
    int kt   = t / (JD / 16);
    int k = kt * 32 + (lane >> 4) * 8 + j;
    int n = nt * 16 + (lane & 15);
    P[o] = f2bf(W[(size_t)k * JD + n]);
}

// ---- pull-style mean aggregation, D=128 bf16 -> bf16 -----------------------
__global__ __launch_bounds__(256) void k_agg128b(const unsigned short* __restrict__ in, const int* __restrict__ cnt,
                                                 const int* __restrict__ bucket, uint2* __restrict__ out, int n) {
    int wv   = (blockIdx.x * 256 + threadIdx.x) >> 6;
    int lane = threadIdx.x & 63;
    int g    = lane >> 5;          // node slot in wave
    int li   = lane & 31;
    int node = wv * 2 + g;
    if (node >= n) return;
    int c = cnt[node]; if (c > CAP) c = CAP;
    const uint2* inp = (const uint2*)in;   // row = 32 granules of 8B
    int idxv = 0;
    if (li < c) idxv = bucket[(size_t)node * CAP + li];   // covers s<32
    float a0 = 0.f, a1 = 0.f, a2 = 0.f, a3 = 0.f;
    const int base = g << 5;
    int cc = c < 32 ? c : 32;
    int s = 0;
    for (; s + 4 <= cc; s += 4) {
        int i0 = __shfl(idxv, base + s);
        int i1 = __shfl(idxv, base + s + 1);
        int i2 = __shfl(idxv, base + s + 2);
        int i3 = __shfl(idxv, base + s + 3);
        uint2 v0 = inp[(size_t)i0 * 32 + li];
        uint2 v1 = inp[(size_t)i1 * 32 + li];
        uint2 v2 = inp[(size_t)i2 * 32 + li];
        uint2 v3 = inp[(size_t)i3 * 32 + li];
        a0 += bflo(v0.x) + bflo(v1.x) + bflo(v2.x) + bflo(v3.x);
        a1 += bfhi(v0.x) + bfhi(v1.x) + bfhi(v2.x) + bfhi(v3.x);
        a2 += bflo(v0.y) + bflo(v1.y) + bflo(v2.y) + bflo(v3.y);
        a3 += bfhi(v0.y) + bfhi(v1.y) + bfhi(v2.y) + bfhi(v3.y);
    }
    for (; s < cc; s++) {
        int i0 = __shfl(idxv, base + s);
        uint2 v0 = inp[(size_t)i0 * 32 + li];
        a0 += bflo(v0.x); a1 += bfhi(v0.x); a2 += bflo(v0.y); a3 += bfhi(v0.y);
    }
    for (; s < c; s++) {   // c>32: statistically near-impossible, but correct
        int i0 = bucket[(size_t)node * CAP + s];
        uint2 v0 = inp[(size_t)i0 * 32 + li];
        a0 += bflo(v0.x); a1 += bfhi(v0.x); a2 += bflo(v0.y); a3 += bfhi(v0.y);
    }
    float iv = 1.0f / fmaxf((float)c, 1.0f);
    a0 *= iv; a1 *= iv; a2 *= iv; a3 *= iv;
    uint2 o;
    o.x = (unsigned)f2bf(a0) | ((unsigned)f2bf(a1) << 16);
    o.y = (unsigned)f2bf(a2) | ((unsigned)f2bf(a3) << 16);
    out[(size_t)node * 32 + li] = o;
}

// ---- pull-style mean aggregation, D=64 bf16 -> fp32 ------------------------
__global__ __launch_bounds__(256) void k_agg64b(const unsigned short* __restrict__ in, const int* __restrict__ cnt,
                                                const int* __restrict__ bucket, float4* __restrict__ out, int n) {
    int wv   = (blockIdx.x * 256 + threadIdx.x) >> 6;
    int lane = threadIdx.x & 63;
    int g    = lane >> 4;
    int li   = lane & 15;
    int node = wv * 4 + g;
    if (node >= n) return;
    int c = cnt[node]; if (c > CAP) c = CAP;
    const uint2* inp = (const uint2*)in;   // row = 16 granules of 8B
    int idxv = 0;
    if (li < c) idxv = bucket[(size_t)node * CAP + li];   // covers s<16
    float a0 = 0.f, a1 = 0.f, a2 = 0.f, a3 = 0.f;
    const int base = g << 4;
    int cc = c < 16 ? c : 16;
    int s = 0;
    for (; s + 4 <= cc; s += 4) {
        int i0 = __shfl(idxv, base + s);
        int i1 = __shfl(idxv, base + s + 1);
        int i2 = __shfl(idxv, base + s + 2);
        int i3 = __shfl(idxv, base + s + 3);
        uint2 v0 = inp[(size_t)i0 * 16 + li];
        uint2 v1 = inp[(size_t)i1 * 16 + li];
        uint2 v2 = inp[(size_t)i2 * 16 + li];
        uint2 v3 = inp[(size_t)i3 * 16 + li];
        a0 += bflo(v0.x) + bflo(v1.x) + bflo(v2.x) + bflo(v3.x);
        a1 += bfhi(v0.x) + bfhi(v1.x) + bfhi(v2.x) + bfhi(v3.x);
        a2 += bflo(v0.y) + bflo(v1.y) + bflo(v2.y) + bflo(v3.y);
        a3 += bfhi(v0.y) + bfhi(v1.y) + bfhi(v2.y) + bfhi(v3.y);
    }
    for (; s < cc; s++) {
        int i0 = __shfl(idxv, base + s);
        uint2 v0 = inp[(size_t)i0 * 16 + li];
        a0 += bflo(v0.x); a1 += bfhi(v0.x); a2 += bflo(v0.y); a3 += bfhi(v0.y);
    }
    for (; s < c; s++) {   // c>16 tail (rare)
        int i0 = bucket[(size_t)node * CAP + s];
        uint2 v0 = inp[(size_t)i0 * 16 + li];
        a0 += bflo(v0.x); a1 += bfhi(v0.x); a2 += bflo(v0.y); a3 += bfhi(v0.y);
    }
    float iv = 1.0f / fmaxf((float)c, 1.0f);
    float4 o; o.x = a0 * iv; o.y = a1 * iv; o.z = a2 * iv; o.w = a3 * iv;
    out[(size_t)node * 16 + li] = o;
}

// ---- MFMA GEMM: [nrows x 128] bf16 @ packed B -> [nrows x JD] --------------
// wave tile = 32 rows x 32 cols (2 m-tiles x 2 n-tiles) for max wave count:
// JD=128: 4 col-groups, block covers 32 rows.  JD=64: 2 col-groups x 2 row-groups.
// B frags (16 x 16B) stay VGPR-resident; 32 MFMAs/wave (dual) -> latency hidden by TLP.
template<int JD, bool DUAL, bool RELU, bool ADDD, bool BIAS, bool OUTF, bool OUTB>
__global__ __launch_bounds__(256) void k_mfma(const unsigned short* __restrict__ A, const unsigned short* __restrict__ Bp,
                                              const unsigned short* __restrict__ A2, const unsigned short* __restrict__ B2p,
                                              const float* __restrict__ Dadd, const float* __restrict__ scale,
                                              const float* __restrict__ shift, float* __restrict__ outf,
                                              unsigned short* __restrict__ outb, int nrows) {
    constexpr int NT = JD / 16;     // n-tiles total
    constexpr int CW = JD / 32;     // column-wave-groups (waves per 32-row group)
    constexpr int RG = 4 / CW;      // row-groups per block
    const int tid  = threadIdx.x;
    const int wave = tid >> 6;
    const int lane = tid & 63;
    const int cgrp = wave % CW;
    const int rgrp = wave / CW;
    const int rw0  = (blockIdx.x * RG + rgrp) * 32;
    if (rw0 >= nrows) return;

    const int m = lane & 15;
    const int q = lane >> 4;
    const int rA0 = min(rw0 + m,      nrows - 1);
    const int rA1 = min(rw0 + 16 + m, nrows - 1);
    const int nt0 = cgrp * 2;

    f4v acc[2][2];
    #pragma unroll
    for (int mt = 0; mt < 2; mt++)
        #pragma unroll
        for (int c = 0; c < 2; c++) {
            acc[mt][c][0] = 0.f; acc[mt][c][1] = 0.f; acc[mt][c][2] = 0.f; acc[mt][c][3] = 0.f;
        }

    #pragma unroll
    for (int kt = 0; kt < 4; kt++) {
        const int ko = kt * 32 + q * 8;
        s8v a0 = *(const s8v*)(A + (size_t)rA0 * 128 + ko);
        s8v a1 = *(const s8v*)(A + (size_t)rA1 * 128 + ko);
        #pragma unroll
        for (int c = 0; c < 2; c++) {
            s8v b = *(const s8v*)(Bp + ((size_t)(kt * NT + nt0 + c) * 64 + lane) * 8);
            acc[0][c] = __builtin_amdgcn_mfma_f32_16x16x32_bf16(a0, b, acc[0][c], 0, 0, 0);
            acc[1][c] = __builtin_amdgcn_mfma_f32_16x16x32_bf16(a1, b, acc[1][c], 0, 0, 0);
        }
        if constexpr (DUAL) {
            s8v a0d = *(const s8v*)(A2 + (size_t)rA0 * 128 + ko);
            s8v a1d = *(const s8v*)(A2 + (size_t)rA1 * 128 + ko);
            #pragma unroll
            for (int c = 0; c < 2; c++) {
                s8v b2 = *(const s8v*)(B2p + ((size_t)(kt * NT + nt0 + c) * 64 + lane) * 8);
                acc[0][c] = __builtin_amdgcn_mfma_f32_16x16x32_bf16(a0d, b2, acc[0][c], 0, 0, 0);
                acc[1][c] = __builtin_amdgcn_mfma_f32_16x16x32_bf16(a1d, b2, acc[1][c], 0, 0, 0);
            }
        }
    }

    // epilogue: D element [row = rw0 + mt*16 + q*4 + reg][col = (nt0+c)*16 + m]
    float scv[2], shv[2];
    #pragma unroll
    for (int c = 0; c < 2; c++) {
        int col = (nt0 + c) * 16 + m;
        if constexpr (RELU) scv[c] = scale[col];
        if constexpr (RELU || BIAS) shv[c] = shift[col];
    }
    #pragma unroll
    for (int mt = 0; mt < 2; mt++) {
        #pragma unroll
        for (int reg = 0; reg < 4; reg++) {
            int row = rw0 + mt * 16 + q * 4 + reg;
            if (row < nrows) {
                #pragma unroll
                for (int c = 0; c < 2; c++) {
                    int col = (nt0 + c) * 16 + m;
                    float v = acc[mt][c][reg];
                    if constexpr (ADDD) v += Dadd[(size_t)row * JD + col];
                    if constexpr (BIAS) v += shv[c];
                    if constexpr (RELU) v = fmaxf(v * scv[c] + shv[c], 0.f);
                    if constexpr (OUTF) outf[(size_t)row * JD + col] = v;
                    if constexpr (OUTB) outb[(size_t)row * JD + col] = f2bf(v);
                }
            }
        }
    }
}

extern "C" void kernel_launch(void* const* d_in, const int* in_sizes, int n_in,
                              void* d_out, int out_size, void* d_ws, size_t ws_size,
                              hipStream_t stream) {
    const float* x   = (const float*)d_in[0];
    const int*   ei  = (const int*)d_in[1];
    const float* Wl1 = (const float*)d_in[2];
    const float* bl1 = (const float*)d_in[3];
    const float* Wr1 = (const float*)d_in[4];
    const float* g1  = (const float*)d_in[5];
    const float* be1 = (const float*)d_in[6];
    const float* rm1 = (const float*)d_in[7];
    const float* rv1 = (const float*)d_in[8];
    const float* Wl2 = (const float*)d_in[9];
    const float* bl2 = (const float*)d_in[10];
    const float* Wr2 = (const float*)d_in[11];
    const float* g2  = (const float*)d_in[12];
    const float* be2 = (const float*)d_in[13];
    const float* rm2 = (const float*)d_in[14];
    const float* rv2 = (const float*)d_in[15];
    const float* Wl3 = (const float*)d_in[16];
    const float* bl3 = (const float*)d_in[17];
    const float* Wr3 = (const float*)d_in[18];

    const int N = in_sizes[0] / 128;
    const int E = in_sizes[1] / 2;
    const int* src = ei;
    const int* dst = ei + E;

    // workspace layout
    char* w = (char*)d_ws;
    auto au = [](size_t v) { return (v + 1023) & ~(size_t)1023; };
    size_t off = 0;
    int*            cnt    = (int*)(w + off);            off += au((size_t)N * 4);
    int*            bucket = (int*)(w + off);            off += au((size_t)N * CAP * 4);
    unsigned short* xb     = (unsigned short*)(w + off); off += au((size_t)N * 128 * 2);
    unsigned short* aggb   = (unsigned short*)(w + off); off += au((size_t)N * 128 * 2);
    unsigned short* hb     = (unsigned short*)(w + off); off += au((size_t)N * 128 * 2);
    unsigned short* hb2    = (unsigned short*)(w + off); off += au((size_t)N * 128 * 2);
    unsigned short* t3b    = (unsigned short*)(w + off); off += au((size_t)N * 64 * 2);
    float*          agg3   = (float*)(w + off);          off += au((size_t)N * 64 * 4);
    unsigned short* Wp[6];
    Wp[0] = (unsigned short*)(w + off); off += au(128 * 128 * 2);  // Wl1
    Wp[1] = (unsigned short*)(w + off); off += au(128 * 128 * 2);  // Wr1
    Wp[2] = (unsigned short*)(w + off); off += au(128 * 128 * 2);  // Wl2
    Wp[3] = (unsigned short*)(w + off); off += au(128 * 128 * 2);  // Wr2
    Wp[4] = (unsigned short*)(w + off); off += au(128 * 64 * 2);   // Wl3
    Wp[5] = (unsigned short*)(w + off); off += au(128 * 64 * 2);   // Wr3
    float* P = (float*)(w + off); off += 2048;
    (void)ws_size; (void)n_in;

    hipMemsetAsync(cnt, 0, (size_t)N * 4, stream);
    k_bucket<<<(E + 255) / 256, 256, 0, stream>>>(src, dst, E, cnt, bucket);
    k_prep<<<1, 128, 0, stream>>>(g1, be1, rm1, rv1, bl1, g2, be2, rm2, rv2, bl2, P);
    dim3 pg(64, 6);
    k_packW<<<pg, 256, 0, stream>>>(Wl1, Wr1, Wl2, Wr2, Wl3, Wr3,
                                    Wp[0], Wp[1], Wp[2], Wp[3], Wp[4], Wp[5]);
    k_cvt<<<((N * 128 / 4) + 255) / 256, 256, 0, stream>>>(x, xb, N * 128 / 4);

    const int agg128Grid = ((size_t)N * 32 + 255) / 256;  // 2 nodes/wave
    const int agg64Grid  = ((size_t)N * 16 + 255) / 256;  // 4 nodes/wave
    const int gemmGrid128 = (N + 31) / 32;                // 32 rows/block (4 col-groups)
    const int gemmGrid64  = (N + 63) / 64;                // 64 rows/block (2 col-groups x 2)

    // layer 1: hb = relu(bn(agg(x)@Wl1 + bl1 + x@Wr1))        [bf16 out]
    k_agg128b<<<agg128Grid, 256, 0, stream>>>(xb, cnt, bucket, (uint2*)aggb, N);
    k_mfma<128, true, true, false, false, false, true><<<gemmGrid128, 256, 0, stream>>>(
        aggb, Wp[0], xb, Wp[1], nullptr, P, P + 128, nullptr, hb, N);

    // layer 2: hb2 = relu(bn(agg(hb)@Wl2 + bl2 + hb@Wr2))     [bf16 out]
    k_agg128b<<<agg128Grid, 256, 0, stream>>>(hb, cnt, bucket, (uint2*)aggb, N);
    k_mfma<128, true, true, false, false, false, true><<<gemmGrid128, 256, 0, stream>>>(
        aggb, Wp[2], hb, Wp[3], nullptr, P + 256, P + 384, nullptr, hb2, N);

    // layer 3: out = agg(hb2@Wl3) + bl3 + hb2@Wr3   (transform-then-aggregate)
    k_mfma<64, false, false, false, false, false, true><<<gemmGrid64, 256, 0, stream>>>(
        hb2, Wp[4], nullptr, nullptr, nullptr, nullptr, nullptr, nullptr, t3b, N);
    k_agg64b<<<agg64Grid, 256, 0, stream>>>(t3b, cnt, bucket, (float4*)agg3, N);
    k_mfma<64, false, false, true, true, true, false><<<gemmGrid64, 256, 0, stream>>>(
        hb2, Wp[5], nullptr, nullptr, agg3, nullptr, bl3, (float*)d_out, nullptr, N);
}

// Round 6
// 296.340 us; speedup vs baseline: 3.0979x; 1.1704x over previous
//
#include <hip/hip_runtime.h>

#define CAP 48

typedef short  s8v  __attribute__((ext_vector_type(8)));
typedef float  f4v  __attribute__((ext_vector_type(4)));

__device__ __forceinline__ unsigned short f2bf(float f) {
    unsigned u = __float_as_uint(f);
    u += 0x7FFFu + ((u >> 16) & 1u);      // RNE
    return (unsigned short)(u >> 16);
}
__device__ __forceinline__ float bflo(unsigned v) { return __uint_as_float(v << 16); }
__device__ __forceinline__ float bfhi(unsigned v) { return __uint_as_float(v & 0xffff0000u); }

// ---- build bucketed CSR (by dst) -------------------------------------------
__global__ __launch_bounds__(256) void k_bucket(const int* __restrict__ src, const int* __restrict__ dst,
                                                int E, int* __restrict__ cnt, int* __restrict__ bucket) {
    int e = blockIdx.x * 256 + threadIdx.x;
    if (e < E) {
        int d = dst[e];
        int slot = atomicAdd(&cnt[d], 1);
        if (slot < CAP) bucket[(size_t)d * CAP + slot] = src[e];
    }
}

// ---- merged: pack 6 weights to MFMA B-frag order (y=0..5) + BN fold (y=6) --
__global__ __launch_bounds__(256) void k_prepack(const float* W0, const float* W1, const float* W2,
                                                 const float* W3, const float* W4, const float* W5,
                                                 unsigned short* P0, unsigned short* P1, unsigned short* P2,
                                                 unsigned short* P3, unsigned short* P4, unsigned short* P5,
                                                 const float* g1, const float* be1, const float* rm1, const float* rv1, const float* bl1,
                                                 const float* g2, const float* be2, const float* rm2, const float* rv2, const float* bl2,
                                                 float* P) {
    if (blockIdx.y == 6) {
        if (blockIdx.x == 0 && threadIdx.x < 128) {
            int j = threadIdx.x;
            float s1 = g1[j] * rsqrtf(rv1[j] + 1e-5f);
            P[j]       = s1;
            P[128 + j] = (bl1[j] - rm1[j]) * s1 + be1[j];
            float s2 = g2[j] * rsqrtf(rv2[j] + 1e-5f);
            P[256 + j] = s2;
            P[384 + j] = (bl2[j] - rm2[j]) * s2 + be2[j];
        }
        return;
    }
    const float* W; unsigned short* Pk; int JD;
    switch (blockIdx.y) {
        case 0: W = W0; Pk = P0; JD = 128; break;
        case 1: W = W1; Pk = P1; JD = 128; break;
        case 2: W = W2; Pk = P2; JD = 128; break;
        case 3: W = W3; Pk = P3; JD = 128; break;
        case 4: W = W4; Pk = P4; JD = 64;  break;
        default:W = W5; Pk = P5; JD = 64;  break;
    }
    int o = blockIdx.x * 256 + threadIdx.x;
    if (o >= 128 * JD) return;
    int j    = o & 7;
    int lane = (o >> 3) & 63;
    int t    = o >> 9;
    int nt   = t % (JD / 16);
    int kt   = t / (JD / 16);
    int k = kt * 32 + (lane >> 4) * 8 + j;
    int n = nt * 16 + (lane & 15);
    Pk[o] = f2bf(W[(size_t)k * JD + n]);
}

// ---- fp32 -> bf16 row-major convert ----------------------------------------
__global__ __launch_bounds__(256) void k_cvt(const float* __restrict__ in, unsigned short* __restrict__ out, int n4) {
    int i = blockIdx.x * 256 + threadIdx.x;
    if (i < n4) {
        float4 v = ((const float4*)in)[i];
        ushort4 o;
        o.x = f2bf(v.x); o.y = f2bf(v.y); o.z = f2bf(v.z); o.w = f2bf(v.w);
        ((ushort4*)out)[i] = o;
    }
}

// ---- fused SAGE layer: gather-mean -> LDS, dual MFMA, BN+ReLU epilogue -----
// block = 32 nodes, 4 waves. T3: also compute t3 = out_tile @ W3p (layer-2 only).
// LDS row stride 136 shorts: A-frag ds_read_b128 lands 2-way on banks (free).
template<bool T3>
__global__ __launch_bounds__(256) void k_fused(const unsigned short* __restrict__ feat,
                                               const int* __restrict__ cnt, const int* __restrict__ bucket,
                                               const unsigned short* __restrict__ Bl, const unsigned short* __restrict__ Br,
                                               const float* __restrict__ scale, const float* __restrict__ shift,
                                               unsigned short* __restrict__ out,
                                               const unsigned short* __restrict__ W3p, unsigned short* __restrict__ t3,
                                               int n) {
    __shared__ unsigned short sA[32 * 136];
    __shared__ unsigned short sH[T3 ? 32 * 136 : 8];
    const int tid  = threadIdx.x;
    const int wave = tid >> 6;
    const int lane = tid & 63;
    const int nb0  = blockIdx.x * 32;
    if (nb0 >= n) return;

    // ---- phase 1: gather-mean, 8 nodes/wave (2 concurrent, 4 pair-iters) ----
    {
        const int g  = lane >> 5;
        const int li = lane & 31;
        const uint2* inp = (const uint2*)feat;     // 256B row = 32 x uint2
        const int base = g << 5;
        #pragma unroll
        for (int p = 0; p < 4; p++) {
            int row  = wave * 8 + p * 2 + g;
            int node = nb0 + row;
            if (node < n) {
                int c = cnt[node]; if (c > CAP) c = CAP;
                int idxv = 0;
                if (li < c) idxv = bucket[(size_t)node * CAP + li];
                float a0 = 0.f, a1 = 0.f, a2 = 0.f, a3 = 0.f;
                int cc = c < 32 ? c : 32;
                int s = 0;
                for (; s + 4 <= cc; s += 4) {
                    int i0 = __shfl(idxv, base + s);
                    int i1 = __shfl(idxv, base + s + 1);
                    int i2 = __shfl(idxv, base + s + 2);
                    int i3 = __shfl(idxv, base + s + 3);
                    uint2 v0 = inp[(size_t)i0 * 32 + li];
                    uint2 v1 = inp[(size_t)i1 * 32 + li];
                    uint2 v2 = inp[(size_t)i2 * 32 + li];
                    uint2 v3 = inp[(size_t)i3 * 32 + li];
                    a0 += bflo(v0.x) + bflo(v1.x) + bflo(v2.x) + bflo(v3.x);
                    a1 += bfhi(v0.x) + bfhi(v1.x) + bfhi(v2.x) + bfhi(v3.x);
                    a2 += bflo(v0.y) + bflo(v1.y) + bflo(v2.y) + bflo(v3.y);
                    a3 += bfhi(v0.y) + bfhi(v1.y) + bfhi(v2.y) + bfhi(v3.y);
                }
                for (; s < cc; s++) {
                    int i0 = __shfl(idxv, base + s);
                    uint2 v0 = inp[(size_t)i0 * 32 + li];
                    a0 += bflo(v0.x); a1 += bfhi(v0.x); a2 += bflo(v0.y); a3 += bfhi(v0.y);
                }
                for (; s < c; s++) {               // deg>32 tail (rare)
                    int i0 = bucket[(size_t)node * CAP + s];
                    uint2 v0 = inp[(size_t)i0 * 32 + li];
                    a0 += bflo(v0.x); a1 += bfhi(v0.x); a2 += bflo(v0.y); a3 += bfhi(v0.y);
                }
                float iv = 1.0f / fmaxf((float)c, 1.0f);
                uint2 o;
                o.x = (unsigned)f2bf(a0 * iv) | ((unsigned)f2bf(a1 * iv) << 16);
                o.y = (unsigned)f2bf(a2 * iv) | ((unsigned)f2bf(a3 * iv) << 16);
                ((uint2*)(sA + row * 136))[li] = o;
            }
        }
    }
    __syncthreads();

    // ---- phase 2: dual MFMA, wave = 32 rows x 32 cols (nt0 = wave*2) --------
    const int m = lane & 15;
    const int q = lane >> 4;
    const int nt0 = wave * 2;
    const int rg0 = min(nb0 + m,      n - 1);
    const int rg1 = min(nb0 + 16 + m, n - 1);

    f4v acc[2][2];
    #pragma unroll
    for (int mt = 0; mt < 2; mt++)
        #pragma unroll
        for (int c = 0; c < 2; c++) {
            acc[mt][c][0] = 0.f; acc[mt][c][1] = 0.f; acc[mt][c][2] = 0.f; acc[mt][c][3] = 0.f;
        }

    #pragma unroll
    for (int kt = 0; kt < 4; kt++) {
        const int ko = kt * 32 + q * 8;
        s8v a0 = *(const s8v*)(sA + m * 136 + ko);          // agg side (LDS)
        s8v a1 = *(const s8v*)(sA + (16 + m) * 136 + ko);
        s8v a0d = *(const s8v*)(feat + (size_t)rg0 * 128 + ko);   // root side (global)
        s8v a1d = *(const s8v*)(feat + (size_t)rg1 * 128 + ko);
        #pragma unroll
        for (int c = 0; c < 2; c++) {
            s8v b  = *(const s8v*)(Bl + ((size_t)(kt * 8 + nt0 + c) * 64 + lane) * 8);
            acc[0][c] = __builtin_amdgcn_mfma_f32_16x16x32_bf16(a0, b, acc[0][c], 0, 0, 0);
            acc[1][c] = __builtin_amdgcn_mfma_f32_16x16x32_bf16(a1, b, acc[1][c], 0, 0, 0);
            s8v b2 = *(const s8v*)(Br + ((size_t)(kt * 8 + nt0 + c) * 64 + lane) * 8);
            acc[0][c] = __builtin_amdgcn_mfma_f32_16x16x32_bf16(a0d, b2, acc[0][c], 0, 0, 0);
            acc[1][c] = __builtin_amdgcn_mfma_f32_16x16x32_bf16(a1d, b2, acc[1][c], 0, 0, 0);
        }
    }

    // ---- epilogue: BN+ReLU, write bf16 (and stash tile for t3) -------------
    float scv[2], shv[2];
    #pragma unroll
    for (int c = 0; c < 2; c++) {
        int col = (nt0 + c) * 16 + m;
        scv[c] = scale[col]; shv[c] = shift[col];
    }
    #pragma unroll
    for (int mt = 0; mt < 2; mt++) {
        #pragma unroll
        for (int reg = 0; reg < 4; reg++) {
            int rloc = mt * 16 + q * 4 + reg;
            int row  = nb0 + rloc;
            if (row < n) {
                #pragma unroll
                for (int c = 0; c < 2; c++) {
                    int col = (nt0 + c) * 16 + m;
                    float v = fmaxf(acc[mt][c][reg] * scv[c] + shv[c], 0.f);
                    unsigned short u = f2bf(v);
                    out[(size_t)row * 128 + col] = u;
                    if constexpr (T3) sH[rloc * 136 + col] = u;
                }
            }
        }
    }

    // ---- phase 3 (layer 2 only): t3 = hb2_tile @ Wl3, wave = 16 cols -------
    if constexpr (T3) {
        __syncthreads();
        f4v a3c[2];
        #pragma unroll
        for (int mt = 0; mt < 2; mt++) { a3c[mt][0] = 0.f; a3c[mt][1] = 0.f; a3c[mt][2] = 0.f; a3c[mt][3] = 0.f; }
        #pragma unroll
        for (int kt = 0; kt < 4; kt++) {
            const int ko = kt * 32 + q * 8;
            s8v a0 = *(const s8v*)(sH + m * 136 + ko);
            s8v a1 = *(const s8v*)(sH + (16 + m) * 136 + ko);
            s8v b  = *(const s8v*)(W3p + ((size_t)(kt * 4 + wave) * 64 + lane) * 8);
            a3c[0] = __builtin_amdgcn_mfma_f32_16x16x32_bf16(a0, b, a3c[0], 0, 0, 0);
            a3c[1] = __builtin_amdgcn_mfma_f32_16x16x32_bf16(a1, b, a3c[1], 0, 0, 0);
        }
        #pragma unroll
        for (int mt = 0; mt < 2; mt++) {
            #pragma unroll
            for (int reg = 0; reg < 4; reg++) {
                int row = nb0 + mt * 16 + q * 4 + reg;
                if (row < n) t3[(size_t)row * 64 + wave * 16 + m] = f2bf(a3c[mt][reg]);
            }
        }
    }
}

// ---- fused layer 3: gather-mean(t3) + hb2@Wr3 + bias -----------------------
// block = 32 nodes, 4 waves; wave = 32 rows x 16 cols.
__global__ __launch_bounds__(256) void k_final(const unsigned short* __restrict__ hb2,
                                               const unsigned short* __restrict__ t3,
                                               const int* __restrict__ cnt, const int* __restrict__ bucket,
                                               const unsigned short* __restrict__ Bp, const float* __restrict__ bias,
                                               float* __restrict__ outf, int n) {
    __shared__ float sG[32 * 68];   // fp32 agg tile, stride 68 (16B-aligned rows)
    const int tid  = threadIdx.x;
    const int wave = tid >> 6;
    const int lane = tid & 63;
    const int nb0  = blockIdx.x * 32;
    if (nb0 >= n) return;

    // ---- phase 1: gather-mean, 8 nodes/wave (4 concurrent, 2 quad-iters) ---
    {
        const int g  = lane >> 4;
        const int li = lane & 15;
        const uint2* inp = (const uint2*)t3;       // 128B row = 16 x uint2
        const int base = g << 4;
        #pragma unroll
        for (int p = 0; p < 2; p++) {
            int row  = wave * 8 + p * 4 + g;
            int node = nb0 + row;
            if (node < n) {
                int c = cnt[node]; if (c > CAP) c = CAP;
                int idxv = 0;
                if (li < c) idxv = bucket[(size_t)node * CAP + li];
                float a0 = 0.f, a1 = 0.f, a2 = 0.f, a3 = 0.f;
                int cc = c < 16 ? c : 16;
                int s = 0;
                for (; s + 4 <= cc; s += 4) {
                    int i0 = __shfl(idxv, base + s);
                    int i1 = __shfl(idxv, base + s + 1);
                    int i2 = __shfl(idxv, base + s + 2);
                    int i3 = __shfl(idxv, base + s + 3);
                    uint2 v0 = inp[(size_t)i0 * 16 + li];
                    uint2 v1 = inp[(size_t)i1 * 16 + li];
                    uint2 v2 = inp[(size_t)i2 * 16 + li];
                    uint2 v3 = inp[(size_t)i3 * 16 + li];
                    a0 += bflo(v0.x) + bflo(v1.x) + bflo(v2.x) + bflo(v3.x);
                    a1 += bfhi(v0.x) + bfhi(v1.x) + bfhi(v2.x) + bfhi(v3.x);
                    a2 += bflo(v0.y) + bflo(v1.y) + bflo(v2.y) + bflo(v3.y);
                    a3 += bfhi(v0.y) + bfhi(v1.y) + bfhi(v2.y) + bfhi(v3.y);
                }
                for (; s < cc; s++) {
                    int i0 = __shfl(idxv, base + s);
                    uint2 v0 = inp[(size_t)i0 * 16 + li];
                    a0 += bflo(v0.x); a1 += bfhi(v0.x); a2 += bflo(v0.y); a3 += bfhi(v0.y);
                }
                for (; s < c; s++) {               // deg>16 tail
                    int i0 = bucket[(size_t)node * CAP + s];
                    uint2 v0 = inp[(size_t)i0 * 16 + li];
                    a0 += bflo(v0.x); a1 += bfhi(v0.x); a2 += bflo(v0.y); a3 += bfhi(v0.y);
                }
                float iv = 1.0f / fmaxf((float)c, 1.0f);
                float4 o; o.x = a0 * iv; o.y = a1 * iv; o.z = a2 * iv; o.w = a3 * iv;
                ((float4*)(sG + row * 68))[li] = o;
            }
        }
    }
    __syncthreads();

    // ---- phase 2: out = hb2 @ Wr3 + agg + bias ------------------------------
    const int m = lane & 15;
    const int q = lane >> 4;
    const int rg0 = min(nb0 + m,      n - 1);
    const int rg1 = min(nb0 + 16 + m, n - 1);

    f4v acc[2];
    #pragma unroll
    for (int mt = 0; mt < 2; mt++) { acc[mt][0] = 0.f; acc[mt][1] = 0.f; acc[mt][2] = 0.f; acc[mt][3] = 0.f; }

    #pragma unroll
    for (int kt = 0; kt < 4; kt++) {
        const int ko = kt * 32 + q * 8;
        s8v a0 = *(const s8v*)(hb2 + (size_t)rg0 * 128 + ko);
        s8v a1 = *(const s8v*)(hb2 + (size_t)rg1 * 128 + ko);
        s8v b  = *(const s8v*)(Bp + ((size_t)(kt * 4 + wave) * 64 + lane) * 8);
        acc[0] = __builtin_amdgcn_mfma_f32_16x16x32_bf16(a0, b, acc[0], 0, 0, 0);
        acc[1] = __builtin_amdgcn_mfma_f32_16x16x32_bf16(a1, b, acc[1], 0, 0, 0);
    }

    const int col = wave * 16 + m;
    const float bv = bias[col];
    #pragma unroll
    for (int mt = 0; mt < 2; mt++) {
        #pragma unroll
        for (int reg = 0; reg < 4; reg++) {
            int rloc = mt * 16 + q * 4 + reg;
            int row  = nb0 + rloc;
            if (row < n) outf[(size_t)row * 64 + col] = acc[mt][reg] + sG[rloc * 68 + col] + bv;
        }
    }
}

extern "C" void kernel_launch(void* const* d_in, const int* in_sizes, int n_in,
                              void* d_out, int out_size, void* d_ws, size_t ws_size,
                              hipStream_t stream) {
    const float* x   = (const float*)d_in[0];
    const int*   ei  = (const int*)d_in[1];
    const float* Wl1 = (const float*)d_in[2];
    const float* bl1 = (const float*)d_in[3];
    const float* Wr1 = (const float*)d_in[4];
    const float* g1  = (const float*)d_in[5];
    const float* be1 = (const float*)d_in[6];
    const float* rm1 = (const float*)d_in[7];
    const float* rv1 = (const float*)d_in[8];
    const float* Wl2 = (const float*)d_in[9];
    const float* bl2 = (const float*)d_in[10];
    const float* Wr2 = (const float*)d_in[11];
    const float* g2  = (const float*)d_in[12];
    const float* be2 = (const float*)d_in[13];
    const float* rm2 = (const float*)d_in[14];
    const float* rv2 = (const float*)d_in[15];
    const float* Wl3 = (const float*)d_in[16];
    const float* bl3 = (const float*)d_in[17];
    const float* Wr3 = (const float*)d_in[18];

    const int N = in_sizes[0] / 128;
    const int E = in_sizes[1] / 2;
    const int* src = ei;
    const int* dst = ei + E;

    // workspace layout
    char* w = (char*)d_ws;
    auto au = [](size_t v) { return (v + 1023) & ~(size_t)1023; };
    size_t off = 0;
    int*            cnt    = (int*)(w + off);            off += au((size_t)N * 4);
    int*            bucket = (int*)(w + off);            off += au((size_t)N * CAP * 4);
    unsigned short* xb     = (unsigned short*)(w + off); off += au((size_t)N * 128 * 2);
    unsigned short* hb     = (unsigned short*)(w + off); off += au((size_t)N * 128 * 2);
    unsigned short* hb2    = (unsigned short*)(w + off); off += au((size_t)N * 128 * 2);
    unsigned short* t3b    = (unsigned short*)(w + off); off += au((size_t)N * 64 * 2);
    unsigned short* Wp[6];
    Wp[0] = (unsigned short*)(w + off); off += au(128 * 128 * 2);  // Wl1
    Wp[1] = (unsigned short*)(w + off); off += au(128 * 128 * 2);  // Wr1
    Wp[2] = (unsigned short*)(w + off); off += au(128 * 128 * 2);  // Wl2
    Wp[3] = (unsigned short*)(w + off); off += au(128 * 128 * 2);  // Wr2
    Wp[4] = (unsigned short*)(w + off); off += au(128 * 64 * 2);   // Wl3
    Wp[5] = (unsigned short*)(w + off); off += au(128 * 64 * 2);   // Wr3
    float* P = (float*)(w + off); off += 2048;
    (void)ws_size; (void)n_in;

    hipMemsetAsync(cnt, 0, (size_t)N * 4, stream);
    k_bucket<<<(E + 255) / 256, 256, 0, stream>>>(src, dst, E, cnt, bucket);
    dim3 pg(64, 7);
    k_prepack<<<pg, 256, 0, stream>>>(Wl1, Wr1, Wl2, Wr2, Wl3, Wr3,
                                      Wp[0], Wp[1], Wp[2], Wp[3], Wp[4], Wp[5],
                                      g1, be1, rm1, rv1, bl1, g2, be2, rm2, rv2, bl2, P);
    k_cvt<<<((N * 128 / 4) + 255) / 256, 256, 0, stream>>>(x, xb, N * 128 / 4);

    const int grid = (N + 31) / 32;

    // layer 1: hb = relu(bn(agg(x)@Wl1 + bl1 + x@Wr1))
    k_fused<false><<<grid, 256, 0, stream>>>(xb, cnt, bucket, Wp[0], Wp[1],
                                             P, P + 128, hb, nullptr, nullptr, N);
    // layer 2: hb2 = relu(bn(agg(hb)@Wl2 + bl2 + hb@Wr2)); t3b = hb2@Wl3
    k_fused<true><<<grid, 256, 0, stream>>>(hb, cnt, bucket, Wp[2], Wp[3],
                                            P + 256, P + 384, hb2, Wp[4], t3b, N);
    // layer 3: out = agg(t3b) + hb2@Wr3 + bl3
    k_final<<<grid, 256, 0, stream>>>(hb2, t3b, cnt, bucket, Wp[5], bl3, (float*)d_out, N);
}

// Round 7
// 293.408 us; speedup vs baseline: 3.1289x; 1.0100x over previous
//
#include <hip/hip_runtime.h>

#define CAP 48

typedef short  s8v  __attribute__((ext_vector_type(8)));
typedef float  f4v  __attribute__((ext_vector_type(4)));

__device__ __forceinline__ unsigned short f2bf(float f) {
    unsigned u = __float_as_uint(f);
    u += 0x7FFFu + ((u >> 16) & 1u);      // RNE
    return (unsigned short)(u >> 16);
}
__device__ __forceinline__ float bflo(unsigned v) { return __uint_as_float(v << 16); }
__device__ __forceinline__ float bfhi(unsigned v) { return __uint_as_float(v & 0xffff0000u); }

#define ACC8(v)  do { a[0]+=bflo((v).x); a[1]+=bfhi((v).x); a[2]+=bflo((v).y); a[3]+=bfhi((v).y); \
                      a[4]+=bflo((v).z); a[5]+=bfhi((v).z); a[6]+=bflo((v).w); a[7]+=bfhi((v).w); } while(0)

// ---- build bucketed CSR (by dst) -------------------------------------------
__global__ __launch_bounds__(256) void k_bucket(const int* __restrict__ src, const int* __restrict__ dst,
                                                int E, int* __restrict__ cnt, int* __restrict__ bucket) {
    int e = blockIdx.x * 256 + threadIdx.x;
    if (e < E) {
        int d = dst[e];
        int slot = atomicAdd(&cnt[d], 1);
        if (slot < CAP) bucket[(size_t)d * CAP + slot] = src[e];
    }
}

// ---- merged: pack 6 weights (y=0..5) + BN fold + zero-row init (y=6) -------
__global__ __launch_bounds__(256) void k_prepack(const float* W0, const float* W1, const float* W2,
                                                 const float* W3, const float* W4, const float* W5,
                                                 unsigned short* P0, unsigned short* P1, unsigned short* P2,
                                                 unsigned short* P3, unsigned short* P4, unsigned short* P5,
                                                 const float* g1, const float* be1, const float* rm1, const float* rv1, const float* bl1,
                                                 const float* g2, const float* be2, const float* rm2, const float* rv2, const float* bl2,
                                                 float* P,
                                                 unsigned short* xb, unsigned short* hb, unsigned short* hb2,
                                                 unsigned short* t3b, int N) {
    if (blockIdx.y == 6) {
        if (blockIdx.x == 0) {
            int i = threadIdx.x;
            if (i < 128) {
                float s1 = g1[i] * rsqrtf(rv1[i] + 1e-5f);
                P[i]       = s1;
                P[128 + i] = (bl1[i] - rm1[i]) * s1 + be1[i];
                float s2 = g2[i] * rsqrtf(rv2[i] + 1e-5f);
                P[256 + i] = s2;
                P[384 + i] = (bl2[i] - rm2[i]) * s2 + be2[i];
                // zero row N of each feature buffer (gather padding target)
                xb [(size_t)N * 128 + i] = 0;
                hb [(size_t)N * 128 + i] = 0;
                hb2[(size_t)N * 128 + i] = 0;
                if (i < 64) t3b[(size_t)N * 64 + i] = 0;
            }
        }
        return;
    }
    const float* W; unsigned short* Pk; int JD;
    switch (blockIdx.y) {
        case 0: W = W0; Pk = P0; JD = 128; break;
        case 1: W = W1; Pk = P1; JD = 128; break;
        case 2: W = W2; Pk = P2; JD = 128; break;
        case 3: W = W3; Pk = P3; JD = 128; break;
        case 4: W = W4; Pk = P4; JD = 64;  break;
        default:W = W5; Pk = P5; JD = 64;  break;
    }
    int o = blockIdx.x * 256 + threadIdx.x;
    if (o >= 128 * JD) return;
    int j    = o & 7;
    int lane = (o >> 3) & 63;
    int t    = o >> 9;
    int nt   = t % (JD / 16);
    int kt   = t / (JD / 16);
    int k = kt * 32 + (lane >> 4) * 8 + j;
    int n = nt * 16 + (lane & 15);
    Pk[o] = f2bf(W[(size_t)k * JD + n]);
}

// ---- fp32 -> bf16 row-major convert ----------------------------------------
__global__ __launch_bounds__(256) void k_cvt(const float* __restrict__ in, unsigned short* __restrict__ out, int n4) {
    int i = blockIdx.x * 256 + threadIdx.x;
    if (i < n4) {
        float4 v = ((const float4*)in)[i];
        ushort4 o;
        o.x = f2bf(v.x); o.y = f2bf(v.y); o.z = f2bf(v.z); o.w = f2bf(v.w);
        ((ushort4*)out)[i] = o;
    }
}

// ---- fused SAGE layer: gather-mean -> LDS, dual MFMA, BN+ReLU epilogue -----
// block = 32 nodes, 4 waves. Gather: quarter-wave per node (16 lanes x uint4),
// 2 serial slots/wave, branch-free unroll-8 rounds via zero-row clamping.
template<bool T3>
__global__ __launch_bounds__(256) void k_fused(const unsigned short* __restrict__ feat,
                                               const int* __restrict__ cnt, const int* __restrict__ bucket,
                                               const unsigned short* __restrict__ Bl, const unsigned short* __restrict__ Br,
                                               const float* __restrict__ scale, const float* __restrict__ shift,
                                               unsigned short* __restrict__ out,
                                               const unsigned short* __restrict__ W3p, unsigned short* __restrict__ t3,
                                               int n) {
    __shared__ unsigned short sA[32 * 136];
    __shared__ unsigned short sH[T3 ? 32 * 136 : 8];
    const int tid  = threadIdx.x;
    const int wave = tid >> 6;
    const int lane = tid & 63;
    const int nb0  = blockIdx.x * 32;
    if (nb0 >= n) return;

    // ---- phase 1: gather-mean ----------------------------------------------
    {
        const int q4   = lane >> 4;
        const int li   = lane & 15;
        const int base = q4 << 4;
        const uint4* inp = (const uint4*)feat;     // 256B row = 16 x uint4
        int rows[2], cs[2], idxs[2];
        #pragma unroll
        for (int t = 0; t < 2; t++) {
            rows[t] = wave * 8 + t * 4 + q4;
            int node = nb0 + rows[t];
            bool ok = node < n;
            int c = ok ? cnt[node] : 0; if (c > CAP) c = CAP;
            cs[t] = c;
            idxs[t] = (ok && li < c) ? bucket[(size_t)node * CAP + li] : n;  // n = zero row
        }
        #pragma unroll
        for (int t = 0; t < 2; t++) {
            const int c = cs[t];
            float a[8] = {0.f, 0.f, 0.f, 0.f, 0.f, 0.f, 0.f, 0.f};
            if (c > 0) {
                #pragma unroll
                for (int u = 0; u < 8; u++) {
                    int idx = __shfl(idxs[t], base + u);        // >=c lanes hold n (zero row)
                    uint4 v = inp[(size_t)idx * 16 + li];
                    ACC8(v);
                }
            }
            if (c > 8) {
                #pragma unroll
                for (int u = 8; u < 16; u++) {
                    int idx = __shfl(idxs[t], base + u);
                    uint4 v = inp[(size_t)idx * 16 + li];
                    ACC8(v);
                }
            }
            const int node = nb0 + rows[t];
            for (int s = 16; s < c; s++) {                      // deg>16 (rare)
                int idx = bucket[(size_t)node * CAP + s];
                uint4 v = inp[(size_t)idx * 16 + li];
                ACC8(v);
            }
            if (node < n) {
                float iv = 1.0f / fmaxf((float)c, 1.0f);
                uint4 o;
                o.x = (unsigned)f2bf(a[0] * iv) | ((unsigned)f2bf(a[1] * iv) << 16);
                o.y = (unsigned)f2bf(a[2] * iv) | ((unsigned)f2bf(a[3] * iv) << 16);
                o.z = (unsigned)f2bf(a[4] * iv) | ((unsigned)f2bf(a[5] * iv) << 16);
                o.w = (unsigned)f2bf(a[6] * iv) | ((unsigned)f2bf(a[7] * iv) << 16);
                *(uint4*)(sA + rows[t] * 136 + li * 8) = o;
            }
        }
    }
    __syncthreads();

    // ---- phase 2: dual MFMA, wave = 32 rows x 32 cols (nt0 = wave*2) --------
    const int m = lane & 15;
    const int q = lane >> 4;
    const int nt0 = wave * 2;
    const int rg0 = min(nb0 + m,      n - 1);
    const int rg1 = min(nb0 + 16 + m, n - 1);

    f4v acc[2][2];
    #pragma unroll
    for (int mt = 0; mt < 2; mt++)
        #pragma unroll
        for (int c = 0; c < 2; c++) {
            acc[mt][c][0] = 0.f; acc[mt][c][1] = 0.f; acc[mt][c][2] = 0.f; acc[mt][c][3] = 0.f;
        }

    #pragma unroll
    for (int kt = 0; kt < 4; kt++) {
        const int ko = kt * 32 + q * 8;
        s8v a0 = *(const s8v*)(sA + m * 136 + ko);                // agg side (LDS)
        s8v a1 = *(const s8v*)(sA + (16 + m) * 136 + ko);
        s8v a0d = *(const s8v*)(feat + (size_t)rg0 * 128 + ko);   // root side (global)
        s8v a1d = *(const s8v*)(feat + (size_t)rg1 * 128 + ko);
        #pragma unroll
        for (int c = 0; c < 2; c++) {
            s8v b  = *(const s8v*)(Bl + ((size_t)(kt * 8 + nt0 + c) * 64 + lane) * 8);
            acc[0][c] = __builtin_amdgcn_mfma_f32_16x16x32_bf16(a0, b, acc[0][c], 0, 0, 0);
            acc[1][c] = __builtin_amdgcn_mfma_f32_16x16x32_bf16(a1, b, acc[1][c], 0, 0, 0);
            s8v b2 = *(const s8v*)(Br + ((size_t)(kt * 8 + nt0 + c) * 64 + lane) * 8);
            acc[0][c] = __builtin_amdgcn_mfma_f32_16x16x32_bf16(a0d, b2, acc[0][c], 0, 0, 0);
            acc[1][c] = __builtin_amdgcn_mfma_f32_16x16x32_bf16(a1d, b2, acc[1][c], 0, 0, 0);
        }
    }

    // ---- epilogue: BN+ReLU, write bf16 (and stash tile for t3) -------------
    float scv[2], shv[2];
    #pragma unroll
    for (int c = 0; c < 2; c++) {
        int col = (nt0 + c) * 16 + m;
        scv[c] = scale[col]; shv[c] = shift[col];
    }
    #pragma unroll
    for (int mt = 0; mt < 2; mt++) {
        #pragma unroll
        for (int reg = 0; reg < 4; reg++) {
            int rloc = mt * 16 + q * 4 + reg;
            int row  = nb0 + rloc;
            if (row < n) {
                #pragma unroll
                for (int c = 0; c < 2; c++) {
                    int col = (nt0 + c) * 16 + m;
                    float v = fmaxf(acc[mt][c][reg] * scv[c] + shv[c], 0.f);
                    unsigned short u = f2bf(v);
                    out[(size_t)row * 128 + col] = u;
                    if constexpr (T3) sH[rloc * 136 + col] = u;
                }
            }
        }
    }

    // ---- phase 3 (layer 2 only): t3 = hb2_tile @ Wl3, wave = 16 cols -------
    if constexpr (T3) {
        __syncthreads();
        f4v a3c[2];
        #pragma unroll
        for (int mt = 0; mt < 2; mt++) { a3c[mt][0] = 0.f; a3c[mt][1] = 0.f; a3c[mt][2] = 0.f; a3c[mt][3] = 0.f; }
        #pragma unroll
        for (int kt = 0; kt < 4; kt++) {
            const int ko = kt * 32 + q * 8;
            s8v a0 = *(const s8v*)(sH + m * 136 + ko);
            s8v a1 = *(const s8v*)(sH + (16 + m) * 136 + ko);
            s8v b  = *(const s8v*)(W3p + ((size_t)(kt * 4 + wave) * 64 + lane) * 8);
            a3c[0] = __builtin_amdgcn_mfma_f32_16x16x32_bf16(a0, b, a3c[0], 0, 0, 0);
            a3c[1] = __builtin_amdgcn_mfma_f32_16x16x32_bf16(a1, b, a3c[1], 0, 0, 0);
        }
        #pragma unroll
        for (int mt = 0; mt < 2; mt++) {
            #pragma unroll
            for (int reg = 0; reg < 4; reg++) {
                int row = nb0 + mt * 16 + q * 4 + reg;
                if (row < n) t3[(size_t)row * 64 + wave * 16 + m] = f2bf(a3c[mt][reg]);
            }
        }
    }
}

// ---- fused layer 3: gather-mean(t3) + hb2@Wr3 + bias -----------------------
// block = 32 nodes, 4 waves. Gather: eighth-wave per node (8 lanes x uint4),
// 8 nodes concurrent per wave, 1 slot, branch-free unroll-8 rounds.
__global__ __launch_bounds__(256) void k_final(const unsigned short* __restrict__ hb2,
                                               const unsigned short* __restrict__ t3,
                                               const int* __restrict__ cnt, const int* __restrict__ bucket,
                                               const unsigned short* __restrict__ Bp, const float* __restrict__ bias,
                                               float* __restrict__ outf, int n) {
    __shared__ float sG[32 * 68];   // fp32 agg tile, stride 68 floats
    const int tid  = threadIdx.x;
    const int wave = tid >> 6;
    const int lane = tid & 63;
    const int nb0  = blockIdx.x * 32;
    if (nb0 >= n) return;

    // ---- phase 1: gather-mean ----------------------------------------------
    {
        const int e8   = lane >> 3;
        const int li   = lane & 7;
        const int base = e8 << 3;
        const uint4* inp = (const uint4*)t3;       // 128B row = 8 x uint4
        const int row  = wave * 8 + e8;
        const int node = nb0 + row;
        const bool ok  = node < n;
        int c = ok ? cnt[node] : 0; if (c > CAP) c = CAP;
        int idx1 = (ok && li < c)     ? bucket[(size_t)node * CAP + li]     : n;
        int idx2 = (ok && li + 8 < c) ? bucket[(size_t)node * CAP + li + 8] : n;
        float a[8] = {0.f, 0.f, 0.f, 0.f, 0.f, 0.f, 0.f, 0.f};
        if (c > 0) {
            #pragma unroll
            for (int u = 0; u < 8; u++) {
                int idx = __shfl(idx1, base + u);
                uint4 v = inp[(size_t)idx * 8 + li];
                ACC8(v);
            }
        }
        if (c > 8) {
            #pragma unroll
            for (int u = 0; u < 8; u++) {
                int idx = __shfl(idx2, base + u);
                uint4 v = inp[(size_t)idx * 8 + li];
                ACC8(v);
            }
        }
        for (int s = 16; s < c; s++) {             // deg>16 (rare)
            int idx = bucket[(size_t)node * CAP + s];
            uint4 v = inp[(size_t)idx * 8 + li];
            ACC8(v);
        }
        if (ok) {
            float iv = 1.0f / fmaxf((float)c, 1.0f);
            float4 o1; o1.x = a[0] * iv; o1.y = a[1] * iv; o1.z = a[2] * iv; o1.w = a[3] * iv;
            float4 o2; o2.x = a[4] * iv; o2.y = a[5] * iv; o2.z = a[6] * iv; o2.w = a[7] * iv;
            *(float4*)(sG + row * 68 + li * 8)     = o1;
            *(float4*)(sG + row * 68 + li * 8 + 4) = o2;
        }
    }
    __syncthreads();

    // ---- phase 2: out = hb2 @ Wr3 + agg + bias ------------------------------
    const int m = lane & 15;
    const int q = lane >> 4;
    const int rg0 = min(nb0 + m,      n - 1);
    const int rg1 = min(nb0 + 16 + m, n - 1);

    f4v acc[2];
    #pragma unroll
    for (int mt = 0; mt < 2; mt++) { acc[mt][0] = 0.f; acc[mt][1] = 0.f; acc[mt][2] = 0.f; acc[mt][3] = 0.f; }

    #pragma unroll
    for (int kt = 0; kt < 4; kt++) {
        const int ko = kt * 32 + q * 8;
        s8v a0 = *(const s8v*)(hb2 + (size_t)rg0 * 128 + ko);
        s8v a1 = *(const s8v*)(hb2 + (size_t)rg1 * 128 + ko);
        s8v b  = *(const s8v*)(Bp + ((size_t)(kt * 4 + wave) * 64 + lane) * 8);
        acc[0] = __builtin_amdgcn_mfma_f32_16x16x32_bf16(a0, b, acc[0], 0, 0, 0);
        acc[1] = __builtin_amdgcn_mfma_f32_16x16x32_bf16(a1, b, acc[1], 0, 0, 0);
    }

    const int col = wave * 16 + m;
    const float bv = bias[col];
    #pragma unroll
    for (int mt = 0; mt < 2; mt++) {
        #pragma unroll
        for (int reg = 0; reg < 4; reg++) {
            int rloc = mt * 16 + q * 4 + reg;
            int row  = nb0 + rloc;
            if (row < n) outf[(size_t)row * 64 + col] = acc[mt][reg] + sG[rloc * 68 + col] + bv;
        }
    }
}

extern "C" void kernel_launch(void* const* d_in, const int* in_sizes, int n_in,
                              void* d_out, int out_size, void* d_ws, size_t ws_size,
                              hipStream_t stream) {
    const float* x   = (const float*)d_in[0];
    const int*   ei  = (const int*)d_in[1];
    const float* Wl1 = (const float*)d_in[2];
    const float* bl1 = (const float*)d_in[3];
    const float* Wr1 = (const float*)d_in[4];
    const float* g1  = (const float*)d_in[5];
    const float* be1 = (const float*)d_in[6];
    const float* rm1 = (const float*)d_in[7];
    const float* rv1 = (const float*)d_in[8];
    const float* Wl2 = (const float*)d_in[9];
    const float* bl2 = (const float*)d_in[10];
    const float* Wr2 = (const float*)d_in[11];
    const float* g2  = (const float*)d_in[12];
    const float* be2 = (const float*)d_in[13];
    const float* rm2 = (const float*)d_in[14];
    const float* rv2 = (const float*)d_in[15];
    const float* Wl3 = (const float*)d_in[16];
    const float* bl3 = (const float*)d_in[17];
    const float* Wr3 = (const float*)d_in[18];

    const int N = in_sizes[0] / 128;
    const int E = in_sizes[1] / 2;
    const int* src = ei;
    const int* dst = ei + E;

    // workspace layout (feature buffers have N+1 rows; row N is the zero row)
    char* w = (char*)d_ws;
    auto au = [](size_t v) { return (v + 1023) & ~(size_t)1023; };
    size_t off = 0;
    int*            cnt    = (int*)(w + off);            off += au((size_t)N * 4);
    int*            bucket = (int*)(w + off);            off += au((size_t)N * CAP * 4);
    unsigned short* xb     = (unsigned short*)(w + off); off += au((size_t)(N + 1) * 128 * 2);
    unsigned short* hb     = (unsigned short*)(w + off); off += au((size_t)(N + 1) * 128 * 2);
    unsigned short* hb2    = (unsigned short*)(w + off); off += au((size_t)(N + 1) * 128 * 2);
    unsigned short* t3b    = (unsigned short*)(w + off); off += au((size_t)(N + 1) * 64 * 2);
    unsigned short* Wp[6];
    Wp[0] = (unsigned short*)(w + off); off += au(128 * 128 * 2);  // Wl1
    Wp[1] = (unsigned short*)(w + off); off += au(128 * 128 * 2);  // Wr1
    Wp[2] = (unsigned short*)(w + off); off += au(128 * 128 * 2);  // Wl2
    Wp[3] = (unsigned short*)(w + off); off += au(128 * 128 * 2);  // Wr2
    Wp[4] = (unsigned short*)(w + off); off += au(128 * 64 * 2);   // Wl3
    Wp[5] = (unsigned short*)(w + off); off += au(128 * 64 * 2);   // Wr3
    float* P = (float*)(w + off); off += 2048;
    (void)ws_size; (void)n_in;

    hipMemsetAsync(cnt, 0, (size_t)N * 4, stream);
    k_bucket<<<(E + 255) / 256, 256, 0, stream>>>(src, dst, E, cnt, bucket);
    dim3 pg(64, 7);
    k_prepack<<<pg, 256, 0, stream>>>(Wl1, Wr1, Wl2, Wr2, Wl3, Wr3,
                                      Wp[0], Wp[1], Wp[2], Wp[3], Wp[4], Wp[5],
                                      g1, be1, rm1, rv1, bl1, g2, be2, rm2, rv2, bl2, P,
                                      xb, hb, hb2, t3b, N);
    k_cvt<<<((N * 128 / 4) + 255) / 256, 256, 0, stream>>>(x, xb, N * 128 / 4);

    const int grid = (N + 31) / 32;

    // layer 1: hb = relu(bn(agg(x)@Wl1 + bl1 + x@Wr1))
    k_fused<false><<<grid, 256, 0, stream>>>(xb, cnt, bucket, Wp[0], Wp[1],
                                             P, P + 128, hb, nullptr, nullptr, N);
    // layer 2: hb2 = relu(bn(agg(hb)@Wl2 + bl2 + hb@Wr2)); t3b = hb2@Wl3
    k_fused<true><<<grid, 256, 0, stream>>>(hb, cnt, bucket, Wp[2], Wp[3],
                                            P + 256, P + 384, hb2, Wp[4], t3b, N);
    // layer 3: out = agg(t3b) + hb2@Wr3 + bl3
    k_final<<<grid, 256, 0, stream>>>(hb2, t3b, cnt, bucket, Wp[5], bl3, (float*)d_out, N);
}